// Round 17
// baseline (152.758 us; speedup 1.0000x reference)
//
#include <hip/hip_runtime.h>
#include <hip/hip_bf16.h>

#define HW 3136

typedef short s16x8 __attribute__((ext_vector_type(8)));
typedef float f32x4 __attribute__((ext_vector_type(4)));
typedef unsigned short us4 __attribute__((ext_vector_type(4)));
typedef unsigned short us8 __attribute__((ext_vector_type(8)));

__device__ inline unsigned short f2bf(float f) {
  union { float f; unsigned int u; } v; v.f = f;
  unsigned int r = v.u + 0x7fff + ((v.u >> 16) & 1);
  return (unsigned short)(r >> 16);
}
__device__ inline float bf2f(unsigned short b) {
  union { unsigned int u; float f; } v; v.u = (unsigned int)b << 16;
  return v.f;
}

// ---------------------------------------------------------------------------
// Weight prep. y=0..2: q_w/k_w/v_w -> plain bf16. y=3: o_w -> hi/lo bf16 pair.
// ---------------------------------------------------------------------------
__global__ __launch_bounds__(256) void wconv_kernel(
    const float* __restrict__ w0, const float* __restrict__ w1,
    const float* __restrict__ w2, const float* __restrict__ w3,
    unsigned short* __restrict__ o0, unsigned short* __restrict__ o1,
    unsigned short* __restrict__ o2, unsigned short* __restrict__ o3h,
    unsigned short* __restrict__ o3l) {
  int i = blockIdx.x * 256 + threadIdx.x;
  int y = blockIdx.y;
  if (y < 3) {
    const float* s = (y == 0) ? w0 : (y == 1) ? w1 : w2;
    unsigned short* d = (y == 0) ? o0 : (y == 1) ? o1 : o2;
    d[i] = f2bf(s[i]);
  } else {
    float x = w3[i];
    unsigned short hi = f2bf(x);
    o3h[i] = hi;
    o3l[i] = f2bf(x - bf2f(hi));
  }
}

// ---------------------------------------------------------------------------
// q-projection MFMA, fused transpose, o-split 2. grid (98, 8), block 128.
// ---------------------------------------------------------------------------
__global__ __launch_bounds__(128) void gemm_q_kernel(
    const float* __restrict__ x, const unsigned short* __restrict__ Wq,
    const float* __restrict__ bias, float* __restrict__ Outf,
    unsigned short* __restrict__ Outb) {
  int by = blockIdx.y;
  int b = by >> 1, oh = by & 1;
  int t = threadIdx.x;
  int w = t >> 6, l = t & 63;
  int lq = l & 15, h = l >> 4;
  int p = blockIdx.x * 32 + w * 16 + lq;

  union S8 { s16x8 v; unsigned short u[8]; };
  S8 bfr[4];
  const float* xs = x + (size_t)b * 128 * HW + p;
  #pragma unroll
  for (int k = 0; k < 4; ++k)
    #pragma unroll
    for (int j = 0; j < 8; ++j)
      bfr[k].u[j] = f2bf(xs[(size_t)(k * 32 + h * 8 + j) * HW]);

  f32x4 acc[4] = {};
  #pragma unroll
  for (int k = 0; k < 4; ++k) {
    #pragma unroll
    for (int ot = 0; ot < 4; ++ot) {
      int og = oh * 4 + ot;
      s16x8 af = *(const s16x8*)&Wq[(size_t)(og * 16 + lq) * 128 + k * 32 + h * 8];
      acc[ot] = __builtin_amdgcn_mfma_f32_16x16x32_bf16(af, bfr[k].v, acc[ot], 0, 0, 0);
    }
  }

  size_t cb = (size_t)b * 128 * HW;
  #pragma unroll
  for (int ot = 0; ot < 4; ++ot) {
    int og = oh * 4 + ot;
    float4 bv = *(const float4*)&bias[og * 16 + h * 4];
    float r[4] = {acc[ot][0] + bv.x, acc[ot][1] + bv.y,
                  acc[ot][2] + bv.z, acc[ot][3] + bv.w};
    #pragma unroll
    for (int i = 0; i < 4; ++i)
      Outf[cb + (size_t)(og * 16 + h * 4 + i) * HW + p] = r[i];
    const float S = 0.25503968151135f;  // rsqrt(32)*log2e
    us4 rb;
    #pragma unroll
    for (int i = 0; i < 4; ++i) rb[i] = f2bf(r[i] * S);
    *(us4*)&Outb[((size_t)b * HW + p) * 128 + og * 16 + h * 4] = rb;
  }
}

// ---------------------------------------------------------------------------
// Fused K+V projection, o-split 2. grid (98, 8), block 128.
// ---------------------------------------------------------------------------
__global__ __launch_bounds__(128) void gemm_kv_kernel(
    const unsigned short* __restrict__ InT, const unsigned short* __restrict__ Wk,
    const unsigned short* __restrict__ Wv, const float* __restrict__ k_b,
    const float* __restrict__ v_b, unsigned short* __restrict__ kbT,
    unsigned short* __restrict__ vb) {
  int by = blockIdx.y;
  int b = by >> 1, oh = by & 1;
  int t = threadIdx.x;
  int w = t >> 6, l = t & 63;
  int lq = l & 15, h = l >> 4;
  int p = blockIdx.x * 32 + w * 16 + lq;

  s16x8 bfr[4];
  const unsigned short* bsrc = InT + ((size_t)b * HW + p) * 128 + h * 8;
  #pragma unroll
  for (int k = 0; k < 4; ++k) bfr[k] = *(const s16x8*)&bsrc[k * 32];

  {
    f32x4 acc[4] = {};
    #pragma unroll
    for (int k = 0; k < 4; ++k) {
      #pragma unroll
      for (int ot = 0; ot < 4; ++ot) {
        int og = oh * 4 + ot;
        s16x8 af = *(const s16x8*)&Wk[(size_t)(og * 16 + lq) * 128 + k * 32 + h * 8];
        acc[ot] = __builtin_amdgcn_mfma_f32_16x16x32_bf16(af, bfr[k], acc[ot], 0, 0, 0);
      }
    }
    #pragma unroll
    for (int ot = 0; ot < 4; ++ot) {
      int og = oh * 4 + ot;
      float4 bv = *(const float4*)&k_b[og * 16 + h * 4];
      us4 rb;
      #pragma unroll
      for (int i = 0; i < 4; ++i) rb[i] = f2bf(acc[ot][i] + bv[i]);
      *(us4*)&kbT[((size_t)b * HW + p) * 128 + og * 16 + h * 4] = rb;
    }
  }
  {
    f32x4 acc[4] = {};
    #pragma unroll
    for (int k = 0; k < 4; ++k) {
      #pragma unroll
      for (int ot = 0; ot < 4; ++ot) {
        int og = oh * 4 + ot;
        s16x8 af = *(const s16x8*)&Wv[(size_t)(og * 16 + lq) * 128 + k * 32 + h * 8];
        acc[ot] = __builtin_amdgcn_mfma_f32_16x16x32_bf16(af, bfr[k], acc[ot], 0, 0, 0);
      }
    }
    size_t cb = (size_t)b * 128 * HW;
    #pragma unroll
    for (int ot = 0; ot < 4; ++ot) {
      int og = oh * 4 + ot;
      float4 bv = *(const float4*)&v_b[og * 16 + h * 4];
      #pragma unroll
      for (int i = 0; i < 4; ++i)
        vb[cb + (size_t)(og * 16 + h * 4 + i) * HW + p] = f2bf(acc[ot][i] + bv[i]);
    }
  }
}

// ---------------------------------------------------------------------------
// o-projection MFMA hi/lo, o-split 2. grid (98, 8), block 128.
// ---------------------------------------------------------------------------
__global__ __launch_bounds__(128) void o_gemm_kernel(
    const unsigned short* __restrict__ AHi, const unsigned short* __restrict__ ALo,
    const unsigned short* __restrict__ WHi, const unsigned short* __restrict__ WLo,
    const float* __restrict__ bias, float* __restrict__ Outf) {
  int by = blockIdx.y;
  int b = by >> 1, oh = by & 1;
  int t = threadIdx.x;
  int w = t >> 6, l = t & 63;
  int lq = l & 15, h = l >> 4;
  int p = blockIdx.x * 32 + w * 16 + lq;

  s16x8 bH[4], bL[4];
  const unsigned short* bsH = AHi + ((size_t)b * HW + p) * 128 + h * 8;
  const unsigned short* bsL = ALo + ((size_t)b * HW + p) * 128 + h * 8;
  #pragma unroll
  for (int k = 0; k < 4; ++k) {
    bH[k] = *(const s16x8*)&bsH[k * 32];
    bL[k] = *(const s16x8*)&bsL[k * 32];
  }

  f32x4 acc[4] = {};
  #pragma unroll
  for (int k = 0; k < 4; ++k) {
    #pragma unroll
    for (int ot = 0; ot < 4; ++ot) {
      int og = oh * 4 + ot;
      size_t wi = (size_t)(og * 16 + lq) * 128 + k * 32 + h * 8;
      s16x8 aH = *(const s16x8*)&WHi[wi];
      s16x8 aL = *(const s16x8*)&WLo[wi];
      acc[ot] = __builtin_amdgcn_mfma_f32_16x16x32_bf16(aH, bH[k], acc[ot], 0, 0, 0);
      acc[ot] = __builtin_amdgcn_mfma_f32_16x16x32_bf16(aH, bL[k], acc[ot], 0, 0, 0);
      acc[ot] = __builtin_amdgcn_mfma_f32_16x16x32_bf16(aL, bH[k], acc[ot], 0, 0, 0);
    }
  }

  size_t cb = (size_t)b * 128 * HW;
  #pragma unroll
  for (int ot = 0; ot < 4; ++ot) {
    int og = oh * 4 + ot;
    float4 bv = *(const float4*)&bias[og * 16 + h * 4];
    #pragma unroll
    for (int i = 0; i < 4; ++i)
      Outf[cb + (size_t)(og * 16 + h * 4 + i) * HW + p] = acc[ot][i] + bv[i];
  }
}

// ---------------------------------------------------------------------------
// Offset branch v3 (r15 config): 1024 threads per (bg, h-row). grid (8, 56).
// ---------------------------------------------------------------------------
__global__ __launch_bounds__(1024) void offset_kernel(
    const float* __restrict__ q, const float* __restrict__ dw_w,
    const float* __restrict__ dw_b, const float* __restrict__ ln_g,
    const float* __restrict__ ln_b, const float* __restrict__ off_w,
    float* __restrict__ pos) {
  __shared__ float vs[64][65];
  __shared__ float mu_s[64], rs_s[64];
  __shared__ float part[16][64][2];
  int bg = blockIdx.x, h = blockIdx.y;
  int t = threadIdx.x;
  int w = t & 63;
  int cq = t >> 6;  // 0..15
  int b = bg >> 1, g = bg & 1;
  const float* qb = q + ((size_t)b * 128 + (size_t)g * 64) * HW;

  #pragma unroll
  for (int i = 0; i < 4; ++i) {
    int c = cq * 4 + i;
    float acc = dw_b[c];
    const float* qc = qb + (size_t)c * HW;
    const float* wc = dw_w + c * 49;
    #pragma unroll
    for (int ky = 0; ky < 7; ++ky) {
      int y = h + ky - 3;
      if (y >= 0 && y < 56) {
        #pragma unroll
        for (int kx = 0; kx < 7; ++kx) {
          int xx = w + kx - 3;
          if (xx >= 0 && xx < 56)
            acc += qc[y * 56 + xx] * wc[ky * 7 + kx];
        }
      }
    }
    vs[c][w] = acc;
  }
  __syncthreads();

  if (cq == 0) {
    float sum = 0.f;
    #pragma unroll 8
    for (int c = 0; c < 64; ++c) sum += vs[c][w];
    float mu = sum * 0.015625f;
    float var = 0.f;
    #pragma unroll 8
    for (int c = 0; c < 64; ++c) { float d = vs[c][w] - mu; var += d * d; }
    mu_s[w] = mu;
    rs_s[w] = rsqrtf(var * 0.015625f + 1e-5f);
  }
  __syncthreads();

  {
    float mu = mu_s[w], rstd = rs_s[w];
    float oy = 0.f, ox = 0.f;
    #pragma unroll
    for (int i = 0; i < 4; ++i) {
      int c = cq * 4 + i;
      float hn = (vs[c][w] - mu) * rstd * ln_g[c] + ln_b[c];
      hn = 0.5f * hn * (1.f + erff(hn * 0.70710678118654752f));
      oy += off_w[c] * hn;
      ox += off_w[64 + c] * hn;
    }
    part[cq][w][0] = oy;
    part[cq][w][1] = ox;
  }
  __syncthreads();

  if (cq == 0 && w < 56) {
    float oy = 0.f, ox = 0.f;
    #pragma unroll
    for (int pw = 0; pw < 16; ++pw) {
      oy += part[pw][w][0];
      ox += part[pw][w][1];
    }
    float py = tanhf(oy) * (2.0f / 56.f) + ((h + 0.5f) * (2.f / 56.f) - 1.f);
    float px = tanhf(ox) * (2.0f / 56.f) + ((w + 0.5f) * (2.f / 56.f) - 1.f);
    int idx = bg * HW + h * 56 + w;
    pos[idx * 2 + 0] = (px + 1.f) * 0.5f * 55.f;
    pos[idx * 2 + 1] = (py + 1.f) * 0.5f * 55.f;
  }
}

// ---------------------------------------------------------------------------
// Bilinear grid sample -> bf16 [b][p][128] (unchanged).
// ---------------------------------------------------------------------------
__global__ __launch_bounds__(256) void sample_kernel(
    const float* __restrict__ x, const float* __restrict__ pos,
    unsigned short* __restrict__ xsT) {
  int t = threadIdx.x;
  int p = blockIdx.x * 64 + (t & 63);
  int cg = t >> 6;
  int bg = p / HW, pp = p % HW;
  int b = bg >> 1, g = bg & 1;
  float gx = pos[2 * p], gy = pos[2 * p + 1];
  float x0f = floorf(gx), y0f = floorf(gy);
  float wx1 = gx - x0f, wx0 = 1.f - wx1;
  float wy1 = gy - y0f, wy0 = 1.f - wy1;
  int x0 = (int)x0f, y0 = (int)y0f;
  int x1 = x0 + 1, y1 = y0 + 1;
  float vx0 = (x0 >= 0 && x0 < 56) ? 1.f : 0.f;
  float vx1 = (x1 >= 0 && x1 < 56) ? 1.f : 0.f;
  float vy0 = (y0 >= 0 && y0 < 56) ? 1.f : 0.f;
  float vy1 = (y1 >= 0 && y1 < 56) ? 1.f : 0.f;
  int xc0 = min(max(x0, 0), 55), xc1 = min(max(x1, 0), 55);
  int yc0 = min(max(y0, 0), 55), yc1 = min(max(y1, 0), 55);
  float w00 = wx0 * wy0 * vx0 * vy0, w10 = wx1 * wy0 * vx1 * vy0;
  float w01 = wx0 * wy1 * vx0 * vy1, w11 = wx1 * wy1 * vx1 * vy1;
  int i00 = yc0 * 56 + xc0, i10 = yc0 * 56 + xc1;
  int i01 = yc1 * 56 + xc0, i11 = yc1 * 56 + xc1;
  const float* xb = x + ((size_t)b * 128 + (size_t)g * 64 + cg * 16) * HW;
  unsigned short tmp[16];
  #pragma unroll 4
  for (int i = 0; i < 16; ++i) {
    const float* xc = xb + (size_t)i * HW;
    tmp[i] = f2bf(w00 * xc[i00] + w10 * xc[i10] + w01 * xc[i01] + w11 * xc[i11]);
  }
  unsigned short* dst = xsT + ((size_t)b * HW + pp) * 128 + g * 64 + cg * 16;
  *(us8*)&dst[0] = *(us8*)&tmp[0];
  *(us8*)&dst[8] = *(us8*)&tmp[8];
}

// ---------------------------------------------------------------------------
// MFMA flash attention v17: 64 q-rows PER WAVE (4 fragments), ONE wave per
// block, ZERO barriers. Per K-tile: 4 ds_reads (af kept in regs) feed all
// 16 QK MFMAs; V loads shared by 4 fragments; softmax processed in fragment
// pairs to bound registers. Wave-private dbuf K staged 2 tiles ahead, V
// reg-prefetched 1 ahead, exp2-domain no-max softmax, raw v_exp/cvt_pk.
// grid (49, 16), block 64.
// ---------------------------------------------------------------------------
__global__ __launch_bounds__(64) void attn_mfma_kernel(
    const unsigned short* __restrict__ qT, const unsigned short* __restrict__ kT,
    const unsigned short* __restrict__ vbf, unsigned short* __restrict__ aoHi,
    unsigned short* __restrict__ aoLo) {
  __shared__ __align__(16) unsigned short Klds[2][64][40];
  __shared__ __align__(16) unsigned short Plds[4][16][68];  // [frag][q][kpos]
  const int KSTEP = 64 * 40;
  int bh = blockIdx.y;
  int b = bh >> 2, hd = bh & 3;
  int l = threadIdx.x;  // one wave
  int lq = l & 15, h = l >> 4;
  int q0 = blockIdx.x * 64;
  size_t vbase = (size_t)bh * 32 * HW;

  union S8 { s16x8 v; long long q[2]; unsigned short u[8]; };

  S8 qf[4];
  #pragma unroll
  for (int f = 0; f < 4; ++f)
    qf[f].v = *(const s16x8*)&qT[((size_t)b * HW + q0 + f * 16 + lq) * 128 +
                                 hd * 32 + h * 8];

  // K staging: lane l covers row l, full 32 ch (4 x s16x8).
  const unsigned short* ksrc = kT + ((size_t)b * HW + l) * 128 + hd * 32;
  unsigned short* kdst = &Klds[0][l][0];

  const unsigned short* vl = vbf + vbase + (size_t)lq * HW + h * 8;

  f32x4 oacc[4][2] = {};
  float lsum[4] = {0.f, 0.f, 0.f, 0.f};

  // ---- prologue: stage K(0), issue K(1), prefetch V(0) ----
  S8 kreg[4], vreg[4];
  #pragma unroll
  for (int i = 0; i < 4; ++i) kreg[i].v = *(const s16x8*)&ksrc[i * 8];
  #pragma unroll
  for (int i = 0; i < 4; ++i) *(s16x8*)&kdst[i * 8] = kreg[i].v;
  #pragma unroll
  for (int i = 0; i < 4; ++i)
    kreg[i].v = *(const s16x8*)&ksrc[(size_t)64 * 128 + i * 8];
  #pragma unroll
  for (int c = 0; c < 2; ++c)
    #pragma unroll
    for (int n = 0; n < 2; ++n)
      vreg[c * 2 + n].v = *(const s16x8*)&vl[(size_t)(n * 16) * HW + c * 32];

  for (int tix = 0; tix < 49; ++tix) {
    int cur = tix & 1;
    int kbV = (tix + 1 < 49) ? (tix + 1) * 64 : 0;
    int kbK = (tix + 2 < 49) ? (tix + 2) * 64 : 3072;

    // ---- load K fragments once (4 ds_reads), keep in regs ----
    S8 af[4];
    #pragma unroll
    for (int tt = 0; tt < 4; ++tt)
      af[tt].v = *(const s16x8*)&Klds[cur][tt * 16 + lq][h * 8];

    // ---- write K(t+1) to other buffer; issue K(t+2) loads ----
    #pragma unroll
    for (int i = 0; i < 4; ++i)
      *(s16x8*)(kdst + (cur ^ 1) * KSTEP + i * 8) = kreg[i].v;
    #pragma unroll
    for (int i = 0; i < 4; ++i)
      kreg[i].v = *(const s16x8*)&ksrc[(size_t)kbK * 128 + i * 8];

    // ---- QK + softmax in fragment pairs (st regs reused) ----
    #pragma unroll
    for (int pr = 0; pr < 2; ++pr) {
      f32x4 stA[4], stB[4];
      #pragma unroll
      for (int tt = 0; tt < 4; ++tt) {
        stA[tt] = __builtin_amdgcn_mfma_f32_16x16x32_bf16(
            af[tt].v, qf[pr * 2].v, (f32x4){0.f, 0.f, 0.f, 0.f}, 0, 0, 0);
        stB[tt] = __builtin_amdgcn_mfma_f32_16x16x32_bf16(
            af[tt].v, qf[pr * 2 + 1].v, (f32x4){0.f, 0.f, 0.f, 0.f}, 0, 0, 0);
      }
      #pragma unroll
      for (int tt = 0; tt < 4; ++tt) {
        float a0, a1, a2, a3, b0, b1, b2, b3;
        asm("v_exp_f32 %0, %1" : "=v"(a0) : "v"(stA[tt][0]));
        asm("v_exp_f32 %0, %1" : "=v"(a1) : "v"(stA[tt][1]));
        asm("v_exp_f32 %0, %1" : "=v"(a2) : "v"(stA[tt][2]));
        asm("v_exp_f32 %0, %1" : "=v"(a3) : "v"(stA[tt][3]));
        asm("v_exp_f32 %0, %1" : "=v"(b0) : "v"(stB[tt][0]));
        asm("v_exp_f32 %0, %1" : "=v"(b1) : "v"(stB[tt][1]));
        asm("v_exp_f32 %0, %1" : "=v"(b2) : "v"(stB[tt][2]));
        asm("v_exp_f32 %0, %1" : "=v"(b3) : "v"(stB[tt][3]));
        lsum[pr * 2] += (a0 + a1) + (a2 + a3);
        lsum[pr * 2 + 1] += (b0 + b1) + (b2 + b3);
        unsigned int lo0, hi0, lo1, hi1;
        asm("v_cvt_pk_bf16_f32 %0, %1, %2" : "=v"(lo0) : "v"(a0), "v"(a1));
        asm("v_cvt_pk_bf16_f32 %0, %1, %2" : "=v"(hi0) : "v"(a2), "v"(a3));
        asm("v_cvt_pk_bf16_f32 %0, %1, %2" : "=v"(lo1) : "v"(b0), "v"(b1));
        asm("v_cvt_pk_bf16_f32 %0, %1, %2" : "=v"(hi1) : "v"(b2), "v"(b3));
        unsigned long long pk0 = (unsigned long long)lo0 | ((unsigned long long)hi0 << 32);
        unsigned long long pk1 = (unsigned long long)lo1 | ((unsigned long long)hi1 << 32);
        *(unsigned long long*)&Plds[pr * 2][lq][tt * 16 + h * 4] = pk0;
        *(unsigned long long*)&Plds[pr * 2 + 1][lq][tt * 16 + h * 4] = pk1;
      }
    }

    // ---- PV: 16 MFMAs, V shared by all 4 fragments ----
    #pragma unroll
    for (int c = 0; c < 2; ++c) {
      #pragma unroll
      for (int f = 0; f < 4; ++f) {
        S8 pf;
        pf.q[0] = *(const long long*)&Plds[f][lq][c * 32 + h * 8];
        pf.q[1] = *(const long long*)&Plds[f][lq][c * 32 + h * 8 + 4];
        #pragma unroll
        for (int n = 0; n < 2; ++n)
          oacc[f][n] = __builtin_amdgcn_mfma_f32_16x16x32_bf16(
              vreg[c * 2 + n].v, pf.v, oacc[f][n], 0, 0, 0);
      }
    }

    // ---- prefetch V(t+1) ----
    #pragma unroll
    for (int c = 0; c < 2; ++c)
      #pragma unroll
      for (int n = 0; n < 2; ++n)
        vreg[c * 2 + n].v =
            *(const s16x8*)&vl[(size_t)(n * 16) * HW + kbV + c * 32];
  }

  #pragma unroll
  for (int f = 0; f < 4; ++f) {
    float ls = lsum[f];
    ls += __shfl_xor(ls, 16);
    ls += __shfl_xor(ls, 32);
    float inv = 1.f / ls;
    size_t obase = ((size_t)b * HW + q0 + f * 16 + lq) * 128 + hd * 32;
    #pragma unroll
    for (int n = 0; n < 2; ++n) {
      us4 rh, rl;
      #pragma unroll
      for (int r = 0; r < 4; ++r) {
        float v = oacc[f][n][r] * inv;
        unsigned short hi = f2bf(v);
        rh[r] = hi;
        rl[r] = f2bf(v - bf2f(hi));
      }
      *(us4*)&aoHi[obase + n * 16 + h * 4] = rh;
      *(us4*)&aoLo[obase + n * 16 + h * 4] = rl;
    }
  }
}

// ---------------------------------------------------------------------------
extern "C" void kernel_launch(void* const* d_in, const int* in_sizes, int n_in,
                              void* d_out, int out_size, void* d_ws, size_t ws_size,
                              hipStream_t stream) {
  const float* x    = (const float*)d_in[0];
  const float* dw_w = (const float*)d_in[1];
  const float* dw_b = (const float*)d_in[2];
  const float* ln_g = (const float*)d_in[3];
  const float* ln_b = (const float*)d_in[4];
  const float* offw = (const float*)d_in[5];
  const float* q_w  = (const float*)d_in[6];
  const float* q_b  = (const float*)d_in[7];
  const float* k_w  = (const float*)d_in[8];
  const float* k_b  = (const float*)d_in[9];
  const float* v_w  = (const float*)d_in[10];
  const float* v_b  = (const float*)d_in[11];
  const float* o_w  = (const float*)d_in[12];
  const float* o_b  = (const float*)d_in[13];

  const size_t NE = 1605632;  // 4*128*3136
  float* ws  = (float*)d_ws;
  float* q   = ws;                   // fp32 q [c][p] (offset branch)
  float* pos = q + NE;               // 50176 floats
  unsigned short* xsT  = (unsigned short*)(pos + 50176);  // sampled bf16 [p][128]
  unsigned short* qbT  = xsT + NE;   // q bf16 [p][128] scaled
  unsigned short* kbT  = qbT + NE;   // k bf16 [p][128]
  unsigned short* vb   = kbT + NE;   // v bf16 [c][p]
  unsigned short* aoHi = vb + NE;    // attn out hi bf16 [p][128]
  unsigned short* aoLo = aoHi + NE;  // attn out lo bf16 [p][128]
  unsigned short* Wq   = aoLo + NE;  // 16384 each
  unsigned short* Wk   = Wq + 16384;
  unsigned short* Wv   = Wk + 16384;
  unsigned short* WoH  = Wv + 16384;
  unsigned short* WoL  = WoH + 16384;
  float* out = (float*)d_out;

  wconv_kernel<<<dim3(64, 4), 256, 0, stream>>>(q_w, k_w, v_w, o_w,
                                                Wq, Wk, Wv, WoH, WoL);
  gemm_q_kernel<<<dim3(98, 8), 128, 0, stream>>>(x, Wq, q_b, q, qbT);
  offset_kernel<<<dim3(8, 56), 1024, 0, stream>>>(q, dw_w, dw_b, ln_g, ln_b, offw, pos);
  sample_kernel<<<dim3(392), 256, 0, stream>>>(x, pos, xsT);
  gemm_kv_kernel<<<dim3(98, 8), 128, 0, stream>>>(xsT, Wk, Wv, k_b, v_b, kbT, vb);
  attn_mfma_kernel<<<dim3(49, 16), 64, 0, stream>>>(qbT, kbT, vb, aoHi, aoLo);
  o_gemm_kernel<<<dim3(98, 8), 128, 0, stream>>>(aoHi, aoLo, WoH, WoL, o_b, out);
}

// Round 18
// 147.004 us; speedup vs baseline: 1.0391x; 1.0391x over previous
//
#include <hip/hip_runtime.h>
#include <hip/hip_bf16.h>

#define HW 3136

typedef short s16x8 __attribute__((ext_vector_type(8)));
typedef float f32x4 __attribute__((ext_vector_type(4)));
typedef unsigned short us4 __attribute__((ext_vector_type(4)));
typedef unsigned short us8 __attribute__((ext_vector_type(8)));

__device__ inline unsigned short f2bf(float f) {
  union { float f; unsigned int u; } v; v.f = f;
  unsigned int r = v.u + 0x7fff + ((v.u >> 16) & 1);
  return (unsigned short)(r >> 16);
}
__device__ inline float bf2f(unsigned short b) {
  union { unsigned int u; float f; } v; v.u = (unsigned int)b << 16;
  return v.f;
}

// ---------------------------------------------------------------------------
// Weight prep. y=0..2: q_w/k_w/v_w -> plain bf16. y=3: o_w -> hi/lo bf16 pair.
// ---------------------------------------------------------------------------
__global__ __launch_bounds__(256) void wconv_kernel(
    const float* __restrict__ w0, const float* __restrict__ w1,
    const float* __restrict__ w2, const float* __restrict__ w3,
    unsigned short* __restrict__ o0, unsigned short* __restrict__ o1,
    unsigned short* __restrict__ o2, unsigned short* __restrict__ o3h,
    unsigned short* __restrict__ o3l) {
  int i = blockIdx.x * 256 + threadIdx.x;
  int y = blockIdx.y;
  if (y < 3) {
    const float* s = (y == 0) ? w0 : (y == 1) ? w1 : w2;
    unsigned short* d = (y == 0) ? o0 : (y == 1) ? o1 : o2;
    d[i] = f2bf(s[i]);
  } else {
    float x = w3[i];
    unsigned short hi = f2bf(x);
    o3h[i] = hi;
    o3l[i] = f2bf(x - bf2f(hi));
  }
}

// ---------------------------------------------------------------------------
// q-projection MFMA, fused transpose, o-split 2. grid (98, 8), block 128.
// ---------------------------------------------------------------------------
__global__ __launch_bounds__(128) void gemm_q_kernel(
    const float* __restrict__ x, const unsigned short* __restrict__ Wq,
    const float* __restrict__ bias, float* __restrict__ Outf,
    unsigned short* __restrict__ Outb) {
  int by = blockIdx.y;
  int b = by >> 1, oh = by & 1;
  int t = threadIdx.x;
  int w = t >> 6, l = t & 63;
  int lq = l & 15, h = l >> 4;
  int p = blockIdx.x * 32 + w * 16 + lq;

  union S8 { s16x8 v; unsigned short u[8]; };
  S8 bfr[4];
  const float* xs = x + (size_t)b * 128 * HW + p;
  #pragma unroll
  for (int k = 0; k < 4; ++k)
    #pragma unroll
    for (int j = 0; j < 8; ++j)
      bfr[k].u[j] = f2bf(xs[(size_t)(k * 32 + h * 8 + j) * HW]);

  f32x4 acc[4] = {};
  #pragma unroll
  for (int k = 0; k < 4; ++k) {
    #pragma unroll
    for (int ot = 0; ot < 4; ++ot) {
      int og = oh * 4 + ot;
      s16x8 af = *(const s16x8*)&Wq[(size_t)(og * 16 + lq) * 128 + k * 32 + h * 8];
      acc[ot] = __builtin_amdgcn_mfma_f32_16x16x32_bf16(af, bfr[k].v, acc[ot], 0, 0, 0);
    }
  }

  size_t cb = (size_t)b * 128 * HW;
  #pragma unroll
  for (int ot = 0; ot < 4; ++ot) {
    int og = oh * 4 + ot;
    float4 bv = *(const float4*)&bias[og * 16 + h * 4];
    float r[4] = {acc[ot][0] + bv.x, acc[ot][1] + bv.y,
                  acc[ot][2] + bv.z, acc[ot][3] + bv.w};
    #pragma unroll
    for (int i = 0; i < 4; ++i)
      Outf[cb + (size_t)(og * 16 + h * 4 + i) * HW + p] = r[i];
    const float S = 0.25503968151135f;  // rsqrt(32)*log2e
    us4 rb;
    #pragma unroll
    for (int i = 0; i < 4; ++i) rb[i] = f2bf(r[i] * S);
    *(us4*)&Outb[((size_t)b * HW + p) * 128 + og * 16 + h * 4] = rb;
  }
}

// ---------------------------------------------------------------------------
// Fused K+V projection, o-split 2. grid (98, 8), block 128.
// ---------------------------------------------------------------------------
__global__ __launch_bounds__(128) void gemm_kv_kernel(
    const unsigned short* __restrict__ InT, const unsigned short* __restrict__ Wk,
    const unsigned short* __restrict__ Wv, const float* __restrict__ k_b,
    const float* __restrict__ v_b, unsigned short* __restrict__ kbT,
    unsigned short* __restrict__ vb) {
  int by = blockIdx.y;
  int b = by >> 1, oh = by & 1;
  int t = threadIdx.x;
  int w = t >> 6, l = t & 63;
  int lq = l & 15, h = l >> 4;
  int p = blockIdx.x * 32 + w * 16 + lq;

  s16x8 bfr[4];
  const unsigned short* bsrc = InT + ((size_t)b * HW + p) * 128 + h * 8;
  #pragma unroll
  for (int k = 0; k < 4; ++k) bfr[k] = *(const s16x8*)&bsrc[k * 32];

  {
    f32x4 acc[4] = {};
    #pragma unroll
    for (int k = 0; k < 4; ++k) {
      #pragma unroll
      for (int ot = 0; ot < 4; ++ot) {
        int og = oh * 4 + ot;
        s16x8 af = *(const s16x8*)&Wk[(size_t)(og * 16 + lq) * 128 + k * 32 + h * 8];
        acc[ot] = __builtin_amdgcn_mfma_f32_16x16x32_bf16(af, bfr[k], acc[ot], 0, 0, 0);
      }
    }
    #pragma unroll
    for (int ot = 0; ot < 4; ++ot) {
      int og = oh * 4 + ot;
      float4 bv = *(const float4*)&k_b[og * 16 + h * 4];
      us4 rb;
      #pragma unroll
      for (int i = 0; i < 4; ++i) rb[i] = f2bf(acc[ot][i] + bv[i]);
      *(us4*)&kbT[((size_t)b * HW + p) * 128 + og * 16 + h * 4] = rb;
    }
  }
  {
    f32x4 acc[4] = {};
    #pragma unroll
    for (int k = 0; k < 4; ++k) {
      #pragma unroll
      for (int ot = 0; ot < 4; ++ot) {
        int og = oh * 4 + ot;
        s16x8 af = *(const s16x8*)&Wv[(size_t)(og * 16 + lq) * 128 + k * 32 + h * 8];
        acc[ot] = __builtin_amdgcn_mfma_f32_16x16x32_bf16(af, bfr[k], acc[ot], 0, 0, 0);
      }
    }
    size_t cb = (size_t)b * 128 * HW;
    #pragma unroll
    for (int ot = 0; ot < 4; ++ot) {
      int og = oh * 4 + ot;
      float4 bv = *(const float4*)&v_b[og * 16 + h * 4];
      #pragma unroll
      for (int i = 0; i < 4; ++i)
        vb[cb + (size_t)(og * 16 + h * 4 + i) * HW + p] = f2bf(acc[ot][i] + bv[i]);
    }
  }
}

// ---------------------------------------------------------------------------
// o-projection MFMA hi/lo, o-split 2. grid (98, 8), block 128.
// ---------------------------------------------------------------------------
__global__ __launch_bounds__(128) void o_gemm_kernel(
    const unsigned short* __restrict__ AHi, const unsigned short* __restrict__ ALo,
    const unsigned short* __restrict__ WHi, const unsigned short* __restrict__ WLo,
    const float* __restrict__ bias, float* __restrict__ Outf) {
  int by = blockIdx.y;
  int b = by >> 1, oh = by & 1;
  int t = threadIdx.x;
  int w = t >> 6, l = t & 63;
  int lq = l & 15, h = l >> 4;
  int p = blockIdx.x * 32 + w * 16 + lq;

  s16x8 bH[4], bL[4];
  const unsigned short* bsH = AHi + ((size_t)b * HW + p) * 128 + h * 8;
  const unsigned short* bsL = ALo + ((size_t)b * HW + p) * 128 + h * 8;
  #pragma unroll
  for (int k = 0; k < 4; ++k) {
    bH[k] = *(const s16x8*)&bsH[k * 32];
    bL[k] = *(const s16x8*)&bsL[k * 32];
  }

  f32x4 acc[4] = {};
  #pragma unroll
  for (int k = 0; k < 4; ++k) {
    #pragma unroll
    for (int ot = 0; ot < 4; ++ot) {
      int og = oh * 4 + ot;
      size_t wi = (size_t)(og * 16 + lq) * 128 + k * 32 + h * 8;
      s16x8 aH = *(const s16x8*)&WHi[wi];
      s16x8 aL = *(const s16x8*)&WLo[wi];
      acc[ot] = __builtin_amdgcn_mfma_f32_16x16x32_bf16(aH, bH[k], acc[ot], 0, 0, 0);
      acc[ot] = __builtin_amdgcn_mfma_f32_16x16x32_bf16(aH, bL[k], acc[ot], 0, 0, 0);
      acc[ot] = __builtin_amdgcn_mfma_f32_16x16x32_bf16(aL, bH[k], acc[ot], 0, 0, 0);
    }
  }

  size_t cb = (size_t)b * 128 * HW;
  #pragma unroll
  for (int ot = 0; ot < 4; ++ot) {
    int og = oh * 4 + ot;
    float4 bv = *(const float4*)&bias[og * 16 + h * 4];
    #pragma unroll
    for (int i = 0; i < 4; ++i)
      Outf[cb + (size_t)(og * 16 + h * 4 + i) * HW + p] = acc[ot][i] + bv[i];
  }
}

// ---------------------------------------------------------------------------
// Offset branch v3: 1024 threads per (bg, h-row). grid (8, 56).
// ---------------------------------------------------------------------------
__global__ __launch_bounds__(1024) void offset_kernel(
    const float* __restrict__ q, const float* __restrict__ dw_w,
    const float* __restrict__ dw_b, const float* __restrict__ ln_g,
    const float* __restrict__ ln_b, const float* __restrict__ off_w,
    float* __restrict__ pos) {
  __shared__ float vs[64][65];
  __shared__ float mu_s[64], rs_s[64];
  __shared__ float part[16][64][2];
  int bg = blockIdx.x, h = blockIdx.y;
  int t = threadIdx.x;
  int w = t & 63;
  int cq = t >> 6;  // 0..15
  int b = bg >> 1, g = bg & 1;
  const float* qb = q + ((size_t)b * 128 + (size_t)g * 64) * HW;

  #pragma unroll
  for (int i = 0; i < 4; ++i) {
    int c = cq * 4 + i;
    float acc = dw_b[c];
    const float* qc = qb + (size_t)c * HW;
    const float* wc = dw_w + c * 49;
    #pragma unroll
    for (int ky = 0; ky < 7; ++ky) {
      int y = h + ky - 3;
      if (y >= 0 && y < 56) {
        #pragma unroll
        for (int kx = 0; kx < 7; ++kx) {
          int xx = w + kx - 3;
          if (xx >= 0 && xx < 56)
            acc += qc[y * 56 + xx] * wc[ky * 7 + kx];
        }
      }
    }
    vs[c][w] = acc;
  }
  __syncthreads();

  if (cq == 0) {
    float sum = 0.f;
    #pragma unroll 8
    for (int c = 0; c < 64; ++c) sum += vs[c][w];
    float mu = sum * 0.015625f;
    float var = 0.f;
    #pragma unroll 8
    for (int c = 0; c < 64; ++c) { float d = vs[c][w] - mu; var += d * d; }
    mu_s[w] = mu;
    rs_s[w] = rsqrtf(var * 0.015625f + 1e-5f);
  }
  __syncthreads();

  {
    float mu = mu_s[w], rstd = rs_s[w];
    float oy = 0.f, ox = 0.f;
    #pragma unroll
    for (int i = 0; i < 4; ++i) {
      int c = cq * 4 + i;
      float hn = (vs[c][w] - mu) * rstd * ln_g[c] + ln_b[c];
      hn = 0.5f * hn * (1.f + erff(hn * 0.70710678118654752f));
      oy += off_w[c] * hn;
      ox += off_w[64 + c] * hn;
    }
    part[cq][w][0] = oy;
    part[cq][w][1] = ox;
  }
  __syncthreads();

  if (cq == 0 && w < 56) {
    float oy = 0.f, ox = 0.f;
    #pragma unroll
    for (int pw = 0; pw < 16; ++pw) {
      oy += part[pw][w][0];
      ox += part[pw][w][1];
    }
    float py = tanhf(oy) * (2.0f / 56.f) + ((h + 0.5f) * (2.f / 56.f) - 1.f);
    float px = tanhf(ox) * (2.0f / 56.f) + ((w + 0.5f) * (2.f / 56.f) - 1.f);
    int idx = bg * HW + h * 56 + w;
    pos[idx * 2 + 0] = (px + 1.f) * 0.5f * 55.f;
    pos[idx * 2 + 1] = (py + 1.f) * 0.5f * 55.f;
  }
}

// ---------------------------------------------------------------------------
// Bilinear grid sample -> bf16 [b][p][128] (unchanged).
// ---------------------------------------------------------------------------
__global__ __launch_bounds__(256) void sample_kernel(
    const float* __restrict__ x, const float* __restrict__ pos,
    unsigned short* __restrict__ xsT) {
  int t = threadIdx.x;
  int p = blockIdx.x * 64 + (t & 63);
  int cg = t >> 6;
  int bg = p / HW, pp = p % HW;
  int b = bg >> 1, g = bg & 1;
  float gx = pos[2 * p], gy = pos[2 * p + 1];
  float x0f = floorf(gx), y0f = floorf(gy);
  float wx1 = gx - x0f, wx0 = 1.f - wx1;
  float wy1 = gy - y0f, wy0 = 1.f - wy1;
  int x0 = (int)x0f, y0 = (int)y0f;
  int x1 = x0 + 1, y1 = y0 + 1;
  float vx0 = (x0 >= 0 && x0 < 56) ? 1.f : 0.f;
  float vx1 = (x1 >= 0 && x1 < 56) ? 1.f : 0.f;
  float vy0 = (y0 >= 0 && y0 < 56) ? 1.f : 0.f;
  float vy1 = (y1 >= 0 && y1 < 56) ? 1.f : 0.f;
  int xc0 = min(max(x0, 0), 55), xc1 = min(max(x1, 0), 55);
  int yc0 = min(max(y0, 0), 55), yc1 = min(max(y1, 0), 55);
  float w00 = wx0 * wy0 * vx0 * vy0, w10 = wx1 * wy0 * vx1 * vy0;
  float w01 = wx0 * wy1 * vx0 * vy1, w11 = wx1 * wy1 * vx1 * vy1;
  int i00 = yc0 * 56 + xc0, i10 = yc0 * 56 + xc1;
  int i01 = yc1 * 56 + xc0, i11 = yc1 * 56 + xc1;
  const float* xb = x + ((size_t)b * 128 + (size_t)g * 64 + cg * 16) * HW;
  unsigned short tmp[16];
  #pragma unroll 4
  for (int i = 0; i < 16; ++i) {
    const float* xc = xb + (size_t)i * HW;
    tmp[i] = f2bf(w00 * xc[i00] + w10 * xc[i10] + w01 * xc[i01] + w11 * xc[i11]);
  }
  unsigned short* dst = xsT + ((size_t)b * HW + pp) * 128 + g * 64 + cg * 16;
  *(us8*)&dst[0] = *(us8*)&tmp[0];
  *(us8*)&dst[8] = *(us8*)&tmp[8];
}

// ---------------------------------------------------------------------------
// MFMA flash attention v18: r15 structure (32q/wave, 2 waves/block) with a
// 4-buffer K ring -> ONE barrier per TWO tiles. Super-iteration s handles
// tiles (2s, 2s+1) serially; reads touch bufs {2s&3,(2s+1)&3}, writes touch
// {(2s+2)&3,(2s+3)&3} - disjoint, so the single barrier at the end of s is
// hazard-free (all write->read and read->rewrite pairs cross a barrier).
// Dual kreg (even/odd tiles), V prefetch 1 tile ahead as in r15.
// grid (49, 16), block 128 = 2 waves.
// ---------------------------------------------------------------------------
__global__ __launch_bounds__(128) void attn_mfma_kernel(
    const unsigned short* __restrict__ qT, const unsigned short* __restrict__ kT,
    const unsigned short* __restrict__ vbf, unsigned short* __restrict__ aoHi,
    unsigned short* __restrict__ aoLo) {
  __shared__ __align__(16) unsigned short Klds[4][64][40];
  __shared__ __align__(16) unsigned short Plds[2][2][16][68];  // [wave][frag]
  const int KSTEP = 64 * 40;
  int bh = blockIdx.y;
  int b = bh >> 2, hd = bh & 3;
  int t = threadIdx.x;
  int w = t >> 6, l = t & 63;
  int lq = l & 15, h = l >> 4;
  int q0 = blockIdx.x * 64 + w * 32;
  size_t vbase = (size_t)bh * 32 * HW;

  union S8 { s16x8 v; long long q[2]; unsigned short u[8]; };

  S8 qf0, qf1;
  qf0.v = *(const s16x8*)&qT[((size_t)b * HW + q0 + lq) * 128 + hd * 32 + h * 8];
  qf1.v = *(const s16x8*)&qT[((size_t)b * HW + q0 + 16 + lq) * 128 + hd * 32 + h * 8];

  // K staging: thread t covers row t>>1, 16-ch segment (t&1)*16 of a tile.
  int srow = t >> 1, sseg = (t & 1) * 16;
  const unsigned short* ksrc =
      kT + ((size_t)b * HW + srow) * 128 + hd * 32 + sseg;
  unsigned short* kdst = &Klds[0][srow][sseg];

  const unsigned short* vl = vbf + vbase + (size_t)lq * HW + h * 8;

  f32x4 oacc0[2] = {{0.f, 0.f, 0.f, 0.f}, {0.f, 0.f, 0.f, 0.f}};
  f32x4 oacc1[2] = {{0.f, 0.f, 0.f, 0.f}, {0.f, 0.f, 0.f, 0.f}};
  float lsum0 = 0.f, lsum1 = 0.f;

  // ---- prologue: stage K(0)->buf0, K(1)->buf1; kregE=K(2), kregO=K(3);
  //      prefetch V(0) ----
  S8 kE0, kE1, kO0, kO1, vreg[4];
  {
    S8 a, c;
    a.v = *(const s16x8*)&ksrc[0];
    c.v = *(const s16x8*)&ksrc[8];
    *(s16x8*)&kdst[0] = a.v;
    *(s16x8*)&kdst[8] = c.v;
    a.v = *(const s16x8*)&ksrc[(size_t)64 * 128];
    c.v = *(const s16x8*)&ksrc[(size_t)64 * 128 + 8];
    *(s16x8*)&kdst[KSTEP] = a.v;
    *(s16x8*)&kdst[KSTEP + 8] = c.v;
  }
  kE0.v = *(const s16x8*)&ksrc[(size_t)128 * 128];
  kE1.v = *(const s16x8*)&ksrc[(size_t)128 * 128 + 8];
  kO0.v = *(const s16x8*)&ksrc[(size_t)192 * 128];
  kO1.v = *(const s16x8*)&ksrc[(size_t)192 * 128 + 8];
  #pragma unroll
  for (int c = 0; c < 2; ++c)
    #pragma unroll
    for (int n = 0; n < 2; ++n)
      vreg[c * 2 + n].v = *(const s16x8*)&vl[(size_t)(n * 16) * HW + c * 32];
  asm volatile("s_waitcnt lgkmcnt(0)" ::: "memory");
  __builtin_amdgcn_s_barrier();

  // Per-tile body as a lambda-free macro-ish block, instantiated 2x + tail.
#define ATTN_TILE_BODY(TIX, KREG0, KREG1, DO_STAGE)                          \
  {                                                                          \
    int tix_ = (TIX);                                                        \
    const unsigned short* buf_ = &Klds[tix_ & 3][0][0];                      \
    f32x4 st0[4], st1[4];                                                    \
    _Pragma("unroll")                                                        \
    for (int tt = 0; tt < 4; ++tt) {                                         \
      S8 af;                                                                 \
      af.v = *(const s16x8*)&buf_[(tt * 16 + lq) * 40 + h * 8];              \
      st0[tt] = __builtin_amdgcn_mfma_f32_16x16x32_bf16(                     \
          af.v, qf0.v, (f32x4){0.f, 0.f, 0.f, 0.f}, 0, 0, 0);                \
      st1[tt] = __builtin_amdgcn_mfma_f32_16x16x32_bf16(                     \
          af.v, qf1.v, (f32x4){0.f, 0.f, 0.f, 0.f}, 0, 0, 0);                \
    }                                                                        \
    _Pragma("unroll")                                                        \
    for (int tt = 0; tt < 4; ++tt) {                                         \
      float a0, a1, a2, a3, b0, b1, b2, b3;                                  \
      asm("v_exp_f32 %0, %1" : "=v"(a0) : "v"(st0[tt][0]));                  \
      asm("v_exp_f32 %0, %1" : "=v"(a1) : "v"(st0[tt][1]));                  \
      asm("v_exp_f32 %0, %1" : "=v"(a2) : "v"(st0[tt][2]));                  \
      asm("v_exp_f32 %0, %1" : "=v"(a3) : "v"(st0[tt][3]));                  \
      asm("v_exp_f32 %0, %1" : "=v"(b0) : "v"(st1[tt][0]));                  \
      asm("v_exp_f32 %0, %1" : "=v"(b1) : "v"(st1[tt][1]));                  \
      asm("v_exp_f32 %0, %1" : "=v"(b2) : "v"(st1[tt][2]));                  \
      asm("v_exp_f32 %0, %1" : "=v"(b3) : "v"(st1[tt][3]));                  \
      lsum0 += (a0 + a1) + (a2 + a3);                                        \
      lsum1 += (b0 + b1) + (b2 + b3);                                        \
      unsigned int lo0, hi0, lo1, hi1;                                       \
      asm("v_cvt_pk_bf16_f32 %0, %1, %2" : "=v"(lo0) : "v"(a0), "v"(a1));    \
      asm("v_cvt_pk_bf16_f32 %0, %1, %2" : "=v"(hi0) : "v"(a2), "v"(a3));    \
      asm("v_cvt_pk_bf16_f32 %0, %1, %2" : "=v"(lo1) : "v"(b0), "v"(b1));    \
      asm("v_cvt_pk_bf16_f32 %0, %1, %2" : "=v"(hi1) : "v"(b2), "v"(b3));    \
      unsigned long long pk0 =                                               \
          (unsigned long long)lo0 | ((unsigned long long)hi0 << 32);         \
      unsigned long long pk1 =                                               \
          (unsigned long long)lo1 | ((unsigned long long)hi1 << 32);         \
      *(unsigned long long*)&Plds[w][0][lq][tt * 16 + h * 4] = pk0;          \
      *(unsigned long long*)&Plds[w][1][lq][tt * 16 + h * 4] = pk1;          \
    }                                                                        \
    _Pragma("unroll")                                                        \
    for (int c = 0; c < 2; ++c) {                                            \
      S8 pf0, pf1;                                                           \
      pf0.q[0] = *(const long long*)&Plds[w][0][lq][c * 32 + h * 8];         \
      pf0.q[1] = *(const long long*)&Plds[w][0][lq][c * 32 + h * 8 + 4];     \
      pf1.q[0] = *(const long long*)&Plds[w][1][lq][c * 32 + h * 8];         \
      pf1.q[1] = *(const long long*)&Plds[w][1][lq][c * 32 + h * 8 + 4];     \
      _Pragma("unroll")                                                      \
      for (int n = 0; n < 2; ++n) {                                          \
        oacc0[n] = __builtin_amdgcn_mfma_f32_16x16x32_bf16(                  \
            vreg[c * 2 + n].v, pf0.v, oacc0[n], 0, 0, 0);                    \
        oacc1[n] = __builtin_amdgcn_mfma_f32_16x16x32_bf16(                  \
            vreg[c * 2 + n].v, pf1.v, oacc1[n], 0, 0, 0);                    \
      }                                                                      \
    }                                                                        \
    int kbV_ = (tix_ + 1 < 49) ? (tix_ + 1) * 64 : 0;                        \
    _Pragma("unroll")                                                        \
    for (int c = 0; c < 2; ++c)                                              \
      _Pragma("unroll")                                                      \
      for (int n = 0; n < 2; ++n)                                            \
        vreg[c * 2 + n].v =                                                  \
            *(const s16x8*)&vl[(size_t)(n * 16) * HW + kbV_ + c * 32];       \
    if (DO_STAGE) {                                                          \
      unsigned short* wd_ = kdst + ((tix_ + 2) & 3) * KSTEP;                 \
      *(s16x8*)&wd_[0] = KREG0.v;                                            \
      *(s16x8*)&wd_[8] = KREG1.v;                                            \
      int kbK_ = (tix_ + 4 < 49) ? (tix_ + 4) * 64 : 3072;                   \
      KREG0.v = *(const s16x8*)&ksrc[(size_t)kbK_ * 128];                    \
      KREG1.v = *(const s16x8*)&ksrc[(size_t)kbK_ * 128 + 8];                \
    }                                                                        \
  }

  for (int s = 0; s < 24; ++s) {
    ATTN_TILE_BODY(2 * s, kE0, kE1, true)
    ATTN_TILE_BODY(2 * s + 1, kO0, kO1, true)
    asm volatile("s_waitcnt lgkmcnt(0)" ::: "memory");
    __builtin_amdgcn_s_barrier();
  }
  // tail: tile 48 (buf 0, staged at s=23 tile 46; V(48) prefetched at tile 47)
  ATTN_TILE_BODY(48, kE0, kE1, false)
#undef ATTN_TILE_BODY

  lsum0 += __shfl_xor(lsum0, 16);
  lsum0 += __shfl_xor(lsum0, 32);
  lsum1 += __shfl_xor(lsum1, 16);
  lsum1 += __shfl_xor(lsum1, 32);
  float inv0 = 1.f / lsum0;
  float inv1 = 1.f / lsum1;
  #pragma unroll
  for (int f = 0; f < 2; ++f) {
    float inv = f ? inv1 : inv0;
    f32x4* oacc = f ? oacc1 : oacc0;
    size_t obase = ((size_t)b * HW + q0 + f * 16 + lq) * 128 + hd * 32;
    #pragma unroll
    for (int n = 0; n < 2; ++n) {
      us4 rh, rl;
      #pragma unroll
      for (int r = 0; r < 4; ++r) {
        float v = oacc[n][r] * inv;
        unsigned short hi = f2bf(v);
        rh[r] = hi;
        rl[r] = f2bf(v - bf2f(hi));
      }
      *(us4*)&aoHi[obase + n * 16 + h * 4] = rh;
      *(us4*)&aoLo[obase + n * 16 + h * 4] = rl;
    }
  }
}

// ---------------------------------------------------------------------------
extern "C" void kernel_launch(void* const* d_in, const int* in_sizes, int n_in,
                              void* d_out, int out_size, void* d_ws, size_t ws_size,
                              hipStream_t stream) {
  const float* x    = (const float*)d_in[0];
  const float* dw_w = (const float*)d_in[1];
  const float* dw_b = (const float*)d_in[2];
  const float* ln_g = (const float*)d_in[3];
  const float* ln_b = (const float*)d_in[4];
  const float* offw = (const float*)d_in[5];
  const float* q_w  = (const float*)d_in[6];
  const float* q_b  = (const float*)d_in[7];
  const float* k_w  = (const float*)d_in[8];
  const float* k_b  = (const float*)d_in[9];
  const float* v_w  = (const float*)d_in[10];
  const float* v_b  = (const float*)d_in[11];
  const float* o_w  = (const float*)d_in[12];
  const float* o_b  = (const float*)d_in[13];

  const size_t NE = 1605632;  // 4*128*3136
  float* ws  = (float*)d_ws;
  float* q   = ws;                   // fp32 q [c][p] (offset branch)
  float* pos = q + NE;               // 50176 floats
  unsigned short* xsT  = (unsigned short*)(pos + 50176);  // sampled bf16 [p][128]
  unsigned short* qbT  = xsT + NE;   // q bf16 [p][128] scaled
  unsigned short* kbT  = qbT + NE;   // k bf16 [p][128]
  unsigned short* vb   = kbT + NE;   // v bf16 [c][p]
  unsigned short* aoHi = vb + NE;    // attn out hi bf16 [p][128]
  unsigned short* aoLo = aoHi + NE;  // attn out lo bf16 [p][128]
  unsigned short* Wq   = aoLo + NE;  // 16384 each
  unsigned short* Wk   = Wq + 16384;
  unsigned short* Wv   = Wk + 16384;
  unsigned short* WoH  = Wv + 16384;
  unsigned short* WoL  = WoH + 16384;
  float* out = (float*)d_out;

  wconv_kernel<<<dim3(64, 4), 256, 0, stream>>>(q_w, k_w, v_w, o_w,
                                                Wq, Wk, Wv, WoH, WoL);
  gemm_q_kernel<<<dim3(98, 8), 128, 0, stream>>>(x, Wq, q_b, q, qbT);
  offset_kernel<<<dim3(8, 56), 1024, 0, stream>>>(q, dw_w, dw_b, ln_g, ln_b, offw, pos);
  sample_kernel<<<dim3(392), 256, 0, stream>>>(x, pos, xsT);
  gemm_kv_kernel<<<dim3(98, 8), 128, 0, stream>>>(xsT, Wk, Wv, k_b, v_b, kbT, vb);
  attn_mfma_kernel<<<dim3(49, 16), 128, 0, stream>>>(qbT, kbT, vb, aoHi, aoLo);
  o_gemm_kernel<<<dim3(98, 8), 128, 0, stream>>>(aoHi, aoLo, WoH, WoL, o_b, out);
}

// Round 19
// 136.749 us; speedup vs baseline: 1.1171x; 1.0750x over previous
//
#include <hip/hip_runtime.h>
#include <hip/hip_bf16.h>

#define HW 3136

typedef short s16x8 __attribute__((ext_vector_type(8)));
typedef float f32x4 __attribute__((ext_vector_type(4)));
typedef unsigned short us4 __attribute__((ext_vector_type(4)));
typedef unsigned short us8 __attribute__((ext_vector_type(8)));

__device__ inline unsigned short f2bf(float f) {
  union { float f; unsigned int u; } v; v.f = f;
  unsigned int r = v.u + 0x7fff + ((v.u >> 16) & 1);
  return (unsigned short)(r >> 16);
}
__device__ inline float bf2f(unsigned short b) {
  union { unsigned int u; float f; } v; v.u = (unsigned int)b << 16;
  return v.f;
}

// ---------------------------------------------------------------------------
// Weight prep. y=0..2: q_w/k_w/v_w -> plain bf16. y=3: o_w -> hi/lo bf16 pair.
// ---------------------------------------------------------------------------
__global__ __launch_bounds__(256) void wconv_kernel(
    const float* __restrict__ w0, const float* __restrict__ w1,
    const float* __restrict__ w2, const float* __restrict__ w3,
    unsigned short* __restrict__ o0, unsigned short* __restrict__ o1,
    unsigned short* __restrict__ o2, unsigned short* __restrict__ o3h,
    unsigned short* __restrict__ o3l) {
  int i = blockIdx.x * 256 + threadIdx.x;
  int y = blockIdx.y;
  if (y < 3) {
    const float* s = (y == 0) ? w0 : (y == 1) ? w1 : w2;
    unsigned short* d = (y == 0) ? o0 : (y == 1) ? o1 : o2;
    d[i] = f2bf(s[i]);
  } else {
    float x = w3[i];
    unsigned short hi = f2bf(x);
    o3h[i] = hi;
    o3l[i] = f2bf(x - bf2f(hi));
  }
}

// ---------------------------------------------------------------------------
// q-projection MFMA, fused transpose, o-split 2. grid (98, 8), block 128.
// ---------------------------------------------------------------------------
__global__ __launch_bounds__(128) void gemm_q_kernel(
    const float* __restrict__ x, const unsigned short* __restrict__ Wq,
    const float* __restrict__ bias, float* __restrict__ Outf,
    unsigned short* __restrict__ Outb) {
  int by = blockIdx.y;
  int b = by >> 1, oh = by & 1;
  int t = threadIdx.x;
  int w = t >> 6, l = t & 63;
  int lq = l & 15, h = l >> 4;
  int p = blockIdx.x * 32 + w * 16 + lq;

  union S8 { s16x8 v; unsigned short u[8]; };
  S8 bfr[4];
  const float* xs = x + (size_t)b * 128 * HW + p;
  #pragma unroll
  for (int k = 0; k < 4; ++k)
    #pragma unroll
    for (int j = 0; j < 8; ++j)
      bfr[k].u[j] = f2bf(xs[(size_t)(k * 32 + h * 8 + j) * HW]);

  f32x4 acc[4] = {};
  #pragma unroll
  for (int k = 0; k < 4; ++k) {
    #pragma unroll
    for (int ot = 0; ot < 4; ++ot) {
      int og = oh * 4 + ot;
      s16x8 af = *(const s16x8*)&Wq[(size_t)(og * 16 + lq) * 128 + k * 32 + h * 8];
      acc[ot] = __builtin_amdgcn_mfma_f32_16x16x32_bf16(af, bfr[k].v, acc[ot], 0, 0, 0);
    }
  }

  size_t cb = (size_t)b * 128 * HW;
  #pragma unroll
  for (int ot = 0; ot < 4; ++ot) {
    int og = oh * 4 + ot;
    float4 bv = *(const float4*)&bias[og * 16 + h * 4];
    float r[4] = {acc[ot][0] + bv.x, acc[ot][1] + bv.y,
                  acc[ot][2] + bv.z, acc[ot][3] + bv.w};
    #pragma unroll
    for (int i = 0; i < 4; ++i)
      Outf[cb + (size_t)(og * 16 + h * 4 + i) * HW + p] = r[i];
    const float S = 0.25503968151135f;  // rsqrt(32)*log2e
    us4 rb;
    #pragma unroll
    for (int i = 0; i < 4; ++i) rb[i] = f2bf(r[i] * S);
    *(us4*)&Outb[((size_t)b * HW + p) * 128 + og * 16 + h * 4] = rb;
  }
}

// ---------------------------------------------------------------------------
// Fused K+V projection, o-split 2. grid (98, 8), block 128.
// ---------------------------------------------------------------------------
__global__ __launch_bounds__(128) void gemm_kv_kernel(
    const unsigned short* __restrict__ InT, const unsigned short* __restrict__ Wk,
    const unsigned short* __restrict__ Wv, const float* __restrict__ k_b,
    const float* __restrict__ v_b, unsigned short* __restrict__ kbT,
    unsigned short* __restrict__ vb) {
  int by = blockIdx.y;
  int b = by >> 1, oh = by & 1;
  int t = threadIdx.x;
  int w = t >> 6, l = t & 63;
  int lq = l & 15, h = l >> 4;
  int p = blockIdx.x * 32 + w * 16 + lq;

  s16x8 bfr[4];
  const unsigned short* bsrc = InT + ((size_t)b * HW + p) * 128 + h * 8;
  #pragma unroll
  for (int k = 0; k < 4; ++k) bfr[k] = *(const s16x8*)&bsrc[k * 32];

  {
    f32x4 acc[4] = {};
    #pragma unroll
    for (int k = 0; k < 4; ++k) {
      #pragma unroll
      for (int ot = 0; ot < 4; ++ot) {
        int og = oh * 4 + ot;
        s16x8 af = *(const s16x8*)&Wk[(size_t)(og * 16 + lq) * 128 + k * 32 + h * 8];
        acc[ot] = __builtin_amdgcn_mfma_f32_16x16x32_bf16(af, bfr[k], acc[ot], 0, 0, 0);
      }
    }
    #pragma unroll
    for (int ot = 0; ot < 4; ++ot) {
      int og = oh * 4 + ot;
      float4 bv = *(const float4*)&k_b[og * 16 + h * 4];
      us4 rb;
      #pragma unroll
      for (int i = 0; i < 4; ++i) rb[i] = f2bf(acc[ot][i] + bv[i]);
      *(us4*)&kbT[((size_t)b * HW + p) * 128 + og * 16 + h * 4] = rb;
    }
  }
  {
    f32x4 acc[4] = {};
    #pragma unroll
    for (int k = 0; k < 4; ++k) {
      #pragma unroll
      for (int ot = 0; ot < 4; ++ot) {
        int og = oh * 4 + ot;
        s16x8 af = *(const s16x8*)&Wv[(size_t)(og * 16 + lq) * 128 + k * 32 + h * 8];
        acc[ot] = __builtin_amdgcn_mfma_f32_16x16x32_bf16(af, bfr[k], acc[ot], 0, 0, 0);
      }
    }
    size_t cb = (size_t)b * 128 * HW;
    #pragma unroll
    for (int ot = 0; ot < 4; ++ot) {
      int og = oh * 4 + ot;
      float4 bv = *(const float4*)&v_b[og * 16 + h * 4];
      #pragma unroll
      for (int i = 0; i < 4; ++i)
        vb[cb + (size_t)(og * 16 + h * 4 + i) * HW + p] = f2bf(acc[ot][i] + bv[i]);
    }
  }
}

// ---------------------------------------------------------------------------
// o-projection MFMA hi/lo, o-split 2. grid (98, 8), block 128.
// ---------------------------------------------------------------------------
__global__ __launch_bounds__(128) void o_gemm_kernel(
    const unsigned short* __restrict__ AHi, const unsigned short* __restrict__ ALo,
    const unsigned short* __restrict__ WHi, const unsigned short* __restrict__ WLo,
    const float* __restrict__ bias, float* __restrict__ Outf) {
  int by = blockIdx.y;
  int b = by >> 1, oh = by & 1;
  int t = threadIdx.x;
  int w = t >> 6, l = t & 63;
  int lq = l & 15, h = l >> 4;
  int p = blockIdx.x * 32 + w * 16 + lq;

  s16x8 bH[4], bL[4];
  const unsigned short* bsH = AHi + ((size_t)b * HW + p) * 128 + h * 8;
  const unsigned short* bsL = ALo + ((size_t)b * HW + p) * 128 + h * 8;
  #pragma unroll
  for (int k = 0; k < 4; ++k) {
    bH[k] = *(const s16x8*)&bsH[k * 32];
    bL[k] = *(const s16x8*)&bsL[k * 32];
  }

  f32x4 acc[4] = {};
  #pragma unroll
  for (int k = 0; k < 4; ++k) {
    #pragma unroll
    for (int ot = 0; ot < 4; ++ot) {
      int og = oh * 4 + ot;
      size_t wi = (size_t)(og * 16 + lq) * 128 + k * 32 + h * 8;
      s16x8 aH = *(const s16x8*)&WHi[wi];
      s16x8 aL = *(const s16x8*)&WLo[wi];
      acc[ot] = __builtin_amdgcn_mfma_f32_16x16x32_bf16(aH, bH[k], acc[ot], 0, 0, 0);
      acc[ot] = __builtin_amdgcn_mfma_f32_16x16x32_bf16(aH, bL[k], acc[ot], 0, 0, 0);
      acc[ot] = __builtin_amdgcn_mfma_f32_16x16x32_bf16(aL, bH[k], acc[ot], 0, 0, 0);
    }
  }

  size_t cb = (size_t)b * 128 * HW;
  #pragma unroll
  for (int ot = 0; ot < 4; ++ot) {
    int og = oh * 4 + ot;
    float4 bv = *(const float4*)&bias[og * 16 + h * 4];
    #pragma unroll
    for (int i = 0; i < 4; ++i)
      Outf[cb + (size_t)(og * 16 + h * 4 + i) * HW + p] = acc[ot][i] + bv[i];
  }
}

// ---------------------------------------------------------------------------
// Offset branch v4: horizontal register reuse in the conv phase.
// Block 1024 = 16 waves per (bg, h-row); thread (c = t>>4, wg = t&15):
// wg<14 computes channel c's conv at w = wg*4 .. wg*4+3 from a 7x10 register
// window (<=70 loads for 4 outputs, was 49/output); wg=14/15 zero the
// vs[c][56..63] pad so LN lanes >=56 read zeros. Phases 2-4 as before.
// grid (8, 56).
// ---------------------------------------------------------------------------
__global__ __launch_bounds__(1024) void offset_kernel(
    const float* __restrict__ q, const float* __restrict__ dw_w,
    const float* __restrict__ dw_b, const float* __restrict__ ln_g,
    const float* __restrict__ ln_b, const float* __restrict__ off_w,
    float* __restrict__ pos) {
  __shared__ float vs[64][65];
  __shared__ float mu_s[64], rs_s[64];
  __shared__ float part[16][64][2];
  int bg = blockIdx.x, h = blockIdx.y;
  int t = threadIdx.x;
  int b = bg >> 1, g = bg & 1;
  const float* qb = q + ((size_t)b * 128 + (size_t)g * 64) * HW;

  {
    int c = t >> 4;    // 0..63
    int wg = t & 15;   // 0..15
    if (wg < 14) {
      int w0 = wg * 4;
      float a0 = dw_b[c], a1 = a0, a2 = a0, a3 = a0;
      const float* qc = qb + (size_t)c * HW;
      const float* wc = dw_w + c * 49;
      #pragma unroll
      for (int ky = 0; ky < 7; ++ky) {
        int y = h + ky - 3;
        if (y >= 0 && y < 56) {
          float row[10];
          #pragma unroll
          for (int i = 0; i < 10; ++i) {
            int xx = w0 - 3 + i;
            row[i] = (xx >= 0 && xx < 56) ? qc[y * 56 + xx] : 0.f;
          }
          #pragma unroll
          for (int kx = 0; kx < 7; ++kx) {
            float wv = wc[ky * 7 + kx];
            a0 += row[kx] * wv;
            a1 += row[kx + 1] * wv;
            a2 += row[kx + 2] * wv;
            a3 += row[kx + 3] * wv;
          }
        }
      }
      vs[c][w0 + 0] = a0;
      vs[c][w0 + 1] = a1;
      vs[c][w0 + 2] = a2;
      vs[c][w0 + 3] = a3;
    } else {
      int base = 56 + (wg - 14) * 4;  // 56 or 60
      vs[c][base + 0] = 0.f;
      vs[c][base + 1] = 0.f;
      vs[c][base + 2] = 0.f;
      vs[c][base + 3] = 0.f;
    }
  }
  __syncthreads();

  int w = t & 63;
  int cq = t >> 6;  // 0..15
  if (cq == 0) {
    float sum = 0.f;
    #pragma unroll 8
    for (int c = 0; c < 64; ++c) sum += vs[c][w];
    float mu = sum * 0.015625f;
    float var = 0.f;
    #pragma unroll 8
    for (int c = 0; c < 64; ++c) { float d = vs[c][w] - mu; var += d * d; }
    mu_s[w] = mu;
    rs_s[w] = rsqrtf(var * 0.015625f + 1e-5f);
  }
  __syncthreads();

  {
    float mu = mu_s[w], rstd = rs_s[w];
    float oy = 0.f, ox = 0.f;
    #pragma unroll
    for (int i = 0; i < 4; ++i) {
      int c = cq * 4 + i;
      float hn = (vs[c][w] - mu) * rstd * ln_g[c] + ln_b[c];
      hn = 0.5f * hn * (1.f + erff(hn * 0.70710678118654752f));
      oy += off_w[c] * hn;
      ox += off_w[64 + c] * hn;
    }
    part[cq][w][0] = oy;
    part[cq][w][1] = ox;
  }
  __syncthreads();

  if (cq == 0 && w < 56) {
    float oy = 0.f, ox = 0.f;
    #pragma unroll
    for (int pw = 0; pw < 16; ++pw) {
      oy += part[pw][w][0];
      ox += part[pw][w][1];
    }
    float py = tanhf(oy) * (2.0f / 56.f) + ((h + 0.5f) * (2.f / 56.f) - 1.f);
    float px = tanhf(ox) * (2.0f / 56.f) + ((w + 0.5f) * (2.f / 56.f) - 1.f);
    int idx = bg * HW + h * 56 + w;
    pos[idx * 2 + 0] = (px + 1.f) * 0.5f * 55.f;
    pos[idx * 2 + 1] = (py + 1.f) * 0.5f * 55.f;
  }
}

// ---------------------------------------------------------------------------
// Bilinear grid sample -> bf16 [b][p][128] (unchanged).
// ---------------------------------------------------------------------------
__global__ __launch_bounds__(256) void sample_kernel(
    const float* __restrict__ x, const float* __restrict__ pos,
    unsigned short* __restrict__ xsT) {
  int t = threadIdx.x;
  int p = blockIdx.x * 64 + (t & 63);
  int cg = t >> 6;
  int bg = p / HW, pp = p % HW;
  int b = bg >> 1, g = bg & 1;
  float gx = pos[2 * p], gy = pos[2 * p + 1];
  float x0f = floorf(gx), y0f = floorf(gy);
  float wx1 = gx - x0f, wx0 = 1.f - wx1;
  float wy1 = gy - y0f, wy0 = 1.f - wy1;
  int x0 = (int)x0f, y0 = (int)y0f;
  int x1 = x0 + 1, y1 = y0 + 1;
  float vx0 = (x0 >= 0 && x0 < 56) ? 1.f : 0.f;
  float vx1 = (x1 >= 0 && x1 < 56) ? 1.f : 0.f;
  float vy0 = (y0 >= 0 && y0 < 56) ? 1.f : 0.f;
  float vy1 = (y1 >= 0 && y1 < 56) ? 1.f : 0.f;
  int xc0 = min(max(x0, 0), 55), xc1 = min(max(x1, 0), 55);
  int yc0 = min(max(y0, 0), 55), yc1 = min(max(y1, 0), 55);
  float w00 = wx0 * wy0 * vx0 * vy0, w10 = wx1 * wy0 * vx1 * vy0;
  float w01 = wx0 * wy1 * vx0 * vy1, w11 = wx1 * wy1 * vx1 * vy1;
  int i00 = yc0 * 56 + xc0, i10 = yc0 * 56 + xc1;
  int i01 = yc1 * 56 + xc0, i11 = yc1 * 56 + xc1;
  const float* xb = x + ((size_t)b * 128 + (size_t)g * 64 + cg * 16) * HW;
  unsigned short tmp[16];
  #pragma unroll 4
  for (int i = 0; i < 16; ++i) {
    const float* xc = xb + (size_t)i * HW;
    tmp[i] = f2bf(w00 * xc[i00] + w10 * xc[i10] + w01 * xc[i01] + w11 * xc[i11]);
  }
  unsigned short* dst = xsT + ((size_t)b * HW + pp) * 128 + g * 64 + cg * 16;
  *(us8*)&dst[0] = *(us8*)&tmp[0];
  *(us8*)&dst[8] = *(us8*)&tmp[8];
}

// ---------------------------------------------------------------------------
// MFMA flash attention v15 (r15-exact, the measured best): 32 q-rows per
// wave, 2 waves/block, dbuf K staged 2 ahead, V reg-prefetch 1 ahead,
// lgkm-only barrier, exp2-domain no-max softmax. grid (49, 16), block 128.
// ---------------------------------------------------------------------------
__global__ __launch_bounds__(128) void attn_mfma_kernel(
    const unsigned short* __restrict__ qT, const unsigned short* __restrict__ kT,
    const unsigned short* __restrict__ vbf, unsigned short* __restrict__ aoHi,
    unsigned short* __restrict__ aoLo) {
  __shared__ __align__(16) unsigned short Klds[2][64][40];
  __shared__ __align__(16) unsigned short Plds[2][2][16][68];  // [wave][frag]
  const int KSTEP = 64 * 40;
  int bh = blockIdx.y;
  int b = bh >> 2, hd = bh & 3;
  int t = threadIdx.x;
  int w = t >> 6, l = t & 63;
  int lq = l & 15, h = l >> 4;
  int q0 = blockIdx.x * 64 + w * 32;
  size_t vbase = (size_t)bh * 32 * HW;

  union S8 { s16x8 v; long long q[2]; unsigned short u[8]; };

  S8 qf0, qf1;
  qf0.v = *(const s16x8*)&qT[((size_t)b * HW + q0 + lq) * 128 + hd * 32 + h * 8];
  qf1.v = *(const s16x8*)&qT[((size_t)b * HW + q0 + 16 + lq) * 128 + hd * 32 + h * 8];

  int srow = t >> 1, sseg = (t & 1) * 16;
  const unsigned short* ksrc =
      kT + ((size_t)b * HW + srow) * 128 + hd * 32 + sseg;
  unsigned short* kdst = &Klds[0][srow][sseg];

  const unsigned short* vl = vbf + vbase + (size_t)lq * HW + h * 8;

  f32x4 oacc0[2] = {{0.f, 0.f, 0.f, 0.f}, {0.f, 0.f, 0.f, 0.f}};
  f32x4 oacc1[2] = {{0.f, 0.f, 0.f, 0.f}, {0.f, 0.f, 0.f, 0.f}};
  float lsum0 = 0.f, lsum1 = 0.f;

  S8 kr0, kr1, vreg[4];
  kr0.v = *(const s16x8*)&ksrc[0];
  kr1.v = *(const s16x8*)&ksrc[8];
  *(s16x8*)&kdst[0] = kr0.v;
  *(s16x8*)&kdst[8] = kr1.v;
  kr0.v = *(const s16x8*)&ksrc[(size_t)64 * 128];
  kr1.v = *(const s16x8*)&ksrc[(size_t)64 * 128 + 8];
  #pragma unroll
  for (int c = 0; c < 2; ++c)
    #pragma unroll
    for (int n = 0; n < 2; ++n)
      vreg[c * 2 + n].v = *(const s16x8*)&vl[(size_t)(n * 16) * HW + c * 32];
  asm volatile("s_waitcnt lgkmcnt(0)" ::: "memory");
  __builtin_amdgcn_s_barrier();

  for (int tix = 0; tix < 49; ++tix) {
    int cur = tix & 1;
    int kbV = (tix + 1 < 49) ? (tix + 1) * 64 : 0;
    int kbK = (tix + 2 < 49) ? (tix + 2) * 64 : 3072;

    f32x4 st0[4], st1[4];
    #pragma unroll
    for (int tt = 0; tt < 4; ++tt) {
      S8 af;
      af.v = *(const s16x8*)&Klds[cur][tt * 16 + lq][h * 8];
      st0[tt] = __builtin_amdgcn_mfma_f32_16x16x32_bf16(
          af.v, qf0.v, (f32x4){0.f, 0.f, 0.f, 0.f}, 0, 0, 0);
      st1[tt] = __builtin_amdgcn_mfma_f32_16x16x32_bf16(
          af.v, qf1.v, (f32x4){0.f, 0.f, 0.f, 0.f}, 0, 0, 0);
    }

    #pragma unroll
    for (int tt = 0; tt < 4; ++tt) {
      float a0, a1, a2, a3, b0, b1, b2, b3;
      asm("v_exp_f32 %0, %1" : "=v"(a0) : "v"(st0[tt][0]));
      asm("v_exp_f32 %0, %1" : "=v"(a1) : "v"(st0[tt][1]));
      asm("v_exp_f32 %0, %1" : "=v"(a2) : "v"(st0[tt][2]));
      asm("v_exp_f32 %0, %1" : "=v"(a3) : "v"(st0[tt][3]));
      asm("v_exp_f32 %0, %1" : "=v"(b0) : "v"(st1[tt][0]));
      asm("v_exp_f32 %0, %1" : "=v"(b1) : "v"(st1[tt][1]));
      asm("v_exp_f32 %0, %1" : "=v"(b2) : "v"(st1[tt][2]));
      asm("v_exp_f32 %0, %1" : "=v"(b3) : "v"(st1[tt][3]));
      lsum0 += (a0 + a1) + (a2 + a3);
      lsum1 += (b0 + b1) + (b2 + b3);
      unsigned int lo0, hi0, lo1, hi1;
      asm("v_cvt_pk_bf16_f32 %0, %1, %2" : "=v"(lo0) : "v"(a0), "v"(a1));
      asm("v_cvt_pk_bf16_f32 %0, %1, %2" : "=v"(hi0) : "v"(a2), "v"(a3));
      asm("v_cvt_pk_bf16_f32 %0, %1, %2" : "=v"(lo1) : "v"(b0), "v"(b1));
      asm("v_cvt_pk_bf16_f32 %0, %1, %2" : "=v"(hi1) : "v"(b2), "v"(b3));
      unsigned long long pk0 = (unsigned long long)lo0 | ((unsigned long long)hi0 << 32);
      unsigned long long pk1 = (unsigned long long)lo1 | ((unsigned long long)hi1 << 32);
      *(unsigned long long*)&Plds[w][0][lq][tt * 16 + h * 4] = pk0;
      *(unsigned long long*)&Plds[w][1][lq][tt * 16 + h * 4] = pk1;
    }

    #pragma unroll
    for (int c = 0; c < 2; ++c) {
      S8 pf0, pf1;
      pf0.q[0] = *(const long long*)&Plds[w][0][lq][c * 32 + h * 8];
      pf0.q[1] = *(const long long*)&Plds[w][0][lq][c * 32 + h * 8 + 4];
      pf1.q[0] = *(const long long*)&Plds[w][1][lq][c * 32 + h * 8];
      pf1.q[1] = *(const long long*)&Plds[w][1][lq][c * 32 + h * 8 + 4];
      #pragma unroll
      for (int n = 0; n < 2; ++n) {
        oacc0[n] = __builtin_amdgcn_mfma_f32_16x16x32_bf16(
            vreg[c * 2 + n].v, pf0.v, oacc0[n], 0, 0, 0);
        oacc1[n] = __builtin_amdgcn_mfma_f32_16x16x32_bf16(
            vreg[c * 2 + n].v, pf1.v, oacc1[n], 0, 0, 0);
      }
    }

    #pragma unroll
    for (int c = 0; c < 2; ++c)
      #pragma unroll
      for (int n = 0; n < 2; ++n)
        vreg[c * 2 + n].v =
            *(const s16x8*)&vl[(size_t)(n * 16) * HW + kbV + c * 32];

    *(s16x8*)(kdst + (cur ^ 1) * KSTEP) = kr0.v;
    *(s16x8*)(kdst + (cur ^ 1) * KSTEP + 8) = kr1.v;
    kr0.v = *(const s16x8*)&ksrc[(size_t)kbK * 128];
    kr1.v = *(const s16x8*)&ksrc[(size_t)kbK * 128 + 8];

    asm volatile("s_waitcnt lgkmcnt(0)" ::: "memory");
    __builtin_amdgcn_s_barrier();
  }

  lsum0 += __shfl_xor(lsum0, 16);
  lsum0 += __shfl_xor(lsum0, 32);
  lsum1 += __shfl_xor(lsum1, 16);
  lsum1 += __shfl_xor(lsum1, 32);
  float inv0 = 1.f / lsum0;
  float inv1 = 1.f / lsum1;
  #pragma unroll
  for (int f = 0; f < 2; ++f) {
    float inv = f ? inv1 : inv0;
    f32x4* oacc = f ? oacc1 : oacc0;
    size_t obase = ((size_t)b * HW + q0 + f * 16 + lq) * 128 + hd * 32;
    #pragma unroll
    for (int n = 0; n < 2; ++n) {
      us4 rh, rl;
      #pragma unroll
      for (int r = 0; r < 4; ++r) {
        float v = oacc[n][r] * inv;
        unsigned short hi = f2bf(v);
        rh[r] = hi;
        rl[r] = f2bf(v - bf2f(hi));
      }
      *(us4*)&aoHi[obase + n * 16 + h * 4] = rh;
      *(us4*)&aoLo[obase + n * 16 + h * 4] = rl;
    }
  }
}

// ---------------------------------------------------------------------------
extern "C" void kernel_launch(void* const* d_in, const int* in_sizes, int n_in,
                              void* d_out, int out_size, void* d_ws, size_t ws_size,
                              hipStream_t stream) {
  const float* x    = (const float*)d_in[0];
  const float* dw_w = (const float*)d_in[1];
  const float* dw_b = (const float*)d_in[2];
  const float* ln_g = (const float*)d_in[3];
  const float* ln_b = (const float*)d_in[4];
  const float* offw = (const float*)d_in[5];
  const float* q_w  = (const float*)d_in[6];
  const float* q_b  = (const float*)d_in[7];
  const float* k_w  = (const float*)d_in[8];
  const float* k_b  = (const float*)d_in[9];
  const float* v_w  = (const float*)d_in[10];
  const float* v_b  = (const float*)d_in[11];
  const float* o_w  = (const float*)d_in[12];
  const float* o_b  = (const float*)d_in[13];

  const size_t NE = 1605632;  // 4*128*3136
  float* ws  = (float*)d_ws;
  float* q   = ws;                   // fp32 q [c][p] (offset branch)
  float* pos = q + NE;               // 50176 floats
  unsigned short* xsT  = (unsigned short*)(pos + 50176);  // sampled bf16 [p][128]
  unsigned short* qbT  = xsT + NE;   // q bf16 [p][128] scaled
  unsigned short* kbT  = qbT + NE;   // k bf16 [p][128]
  unsigned short* vb   = kbT + NE;   // v bf16 [c][p]
  unsigned short* aoHi = vb + NE;    // attn out hi bf16 [p][128]
  unsigned short* aoLo = aoHi + NE;  // attn out lo bf16 [p][128]
  unsigned short* Wq   = aoLo + NE;  // 16384 each
  unsigned short* Wk   = Wq + 16384;
  unsigned short* Wv   = Wk + 16384;
  unsigned short* WoH  = Wv + 16384;
  unsigned short* WoL  = WoH + 16384;
  float* out = (float*)d_out;

  wconv_kernel<<<dim3(64, 4), 256, 0, stream>>>(q_w, k_w, v_w, o_w,
                                                Wq, Wk, Wv, WoH, WoL);
  gemm_q_kernel<<<dim3(98, 8), 128, 0, stream>>>(x, Wq, q_b, q, qbT);
  offset_kernel<<<dim3(8, 56), 1024, 0, stream>>>(q, dw_w, dw_b, ln_g, ln_b, offw, pos);
  sample_kernel<<<dim3(392), 256, 0, stream>>>(x, pos, xsT);
  gemm_kv_kernel<<<dim3(98, 8), 128, 0, stream>>>(xsT, Wk, Wv, k_b, v_b, kbT, vb);
  attn_mfma_kernel<<<dim3(49, 16), 128, 0, stream>>>(qbT, kbT, vb, aoHi, aoLo);
  o_gemm_kernel<<<dim3(98, 8), 128, 0, stream>>>(aoHi, aoLo, WoH, WoL, o_b, out);
}

// Round 20
// 129.174 us; speedup vs baseline: 1.1826x; 1.0586x over previous
//
#include <hip/hip_runtime.h>
#include <hip/hip_bf16.h>

#define HW 3136

typedef short s16x8 __attribute__((ext_vector_type(8)));
typedef float f32x4 __attribute__((ext_vector_type(4)));
typedef unsigned short us4 __attribute__((ext_vector_type(4)));
typedef unsigned short us8 __attribute__((ext_vector_type(8)));

__device__ inline unsigned short f2bf(float f) {
  union { float f; unsigned int u; } v; v.f = f;
  unsigned int r = v.u + 0x7fff + ((v.u >> 16) & 1);
  return (unsigned short)(r >> 16);
}
__device__ inline float bf2f(unsigned short b) {
  union { unsigned int u; float f; } v; v.u = (unsigned int)b << 16;
  return v.f;
}

// ---------------------------------------------------------------------------
// Weight prep. y=0..2: q_w/k_w/v_w -> plain bf16. y=3: o_w -> hi/lo bf16 pair.
// ---------------------------------------------------------------------------
__global__ __launch_bounds__(256) void wconv_kernel(
    const float* __restrict__ w0, const float* __restrict__ w1,
    const float* __restrict__ w2, const float* __restrict__ w3,
    unsigned short* __restrict__ o0, unsigned short* __restrict__ o1,
    unsigned short* __restrict__ o2, unsigned short* __restrict__ o3h,
    unsigned short* __restrict__ o3l) {
  int i = blockIdx.x * 256 + threadIdx.x;
  int y = blockIdx.y;
  if (y < 3) {
    const float* s = (y == 0) ? w0 : (y == 1) ? w1 : w2;
    unsigned short* d = (y == 0) ? o0 : (y == 1) ? o1 : o2;
    d[i] = f2bf(s[i]);
  } else {
    float x = w3[i];
    unsigned short hi = f2bf(x);
    o3h[i] = hi;
    o3l[i] = f2bf(x - bf2f(hi));
  }
}

// ---------------------------------------------------------------------------
// q-projection MFMA, fused transpose, o-split 2. grid (98, 8), block 128.
// ---------------------------------------------------------------------------
__global__ __launch_bounds__(128) void gemm_q_kernel(
    const float* __restrict__ x, const unsigned short* __restrict__ Wq,
    const float* __restrict__ bias, float* __restrict__ Outf,
    unsigned short* __restrict__ Outb) {
  int by = blockIdx.y;
  int b = by >> 1, oh = by & 1;
  int t = threadIdx.x;
  int w = t >> 6, l = t & 63;
  int lq = l & 15, h = l >> 4;
  int p = blockIdx.x * 32 + w * 16 + lq;

  union S8 { s16x8 v; unsigned short u[8]; };
  S8 bfr[4];
  const float* xs = x + (size_t)b * 128 * HW + p;
  #pragma unroll
  for (int k = 0; k < 4; ++k)
    #pragma unroll
    for (int j = 0; j < 8; ++j)
      bfr[k].u[j] = f2bf(xs[(size_t)(k * 32 + h * 8 + j) * HW]);

  f32x4 acc[4] = {};
  #pragma unroll
  for (int k = 0; k < 4; ++k) {
    #pragma unroll
    for (int ot = 0; ot < 4; ++ot) {
      int og = oh * 4 + ot;
      s16x8 af = *(const s16x8*)&Wq[(size_t)(og * 16 + lq) * 128 + k * 32 + h * 8];
      acc[ot] = __builtin_amdgcn_mfma_f32_16x16x32_bf16(af, bfr[k].v, acc[ot], 0, 0, 0);
    }
  }

  size_t cb = (size_t)b * 128 * HW;
  #pragma unroll
  for (int ot = 0; ot < 4; ++ot) {
    int og = oh * 4 + ot;
    float4 bv = *(const float4*)&bias[og * 16 + h * 4];
    float r[4] = {acc[ot][0] + bv.x, acc[ot][1] + bv.y,
                  acc[ot][2] + bv.z, acc[ot][3] + bv.w};
    #pragma unroll
    for (int i = 0; i < 4; ++i)
      Outf[cb + (size_t)(og * 16 + h * 4 + i) * HW + p] = r[i];
    const float S = 0.25503968151135f;  // rsqrt(32)*log2e
    us4 rb;
    #pragma unroll
    for (int i = 0; i < 4; ++i) rb[i] = f2bf(r[i] * S);
    *(us4*)&Outb[((size_t)b * HW + p) * 128 + og * 16 + h * 4] = rb;
  }
}

// ---------------------------------------------------------------------------
// FUSED bilinear-sample + K/V projection. grid (98, 4), block 256 = 4 waves.
// Phase 1: thread (pp = t&31, cg = t>>5) samples 16 channels of position
//   p0+pp into LDS xls[32][136] bf16 (pad: stride 68 dw == 4 mod 32 ->
//   <=2-way read conflicts; rows 16B-aligned).
// Phase 2: wave w owns o-range [32w, 32w+32); K and V GEMMs read fragments
//   from LDS. Epilogues identical to the old gemm_kv (K -> bf16 [p][o],
//   V -> bf16 [c][p]). Numerics identical to sample->xsT->gemm_kv.
// ---------------------------------------------------------------------------
__global__ __launch_bounds__(256) void sample_kv_kernel(
    const float* __restrict__ x, const float* __restrict__ pos,
    const unsigned short* __restrict__ Wk, const unsigned short* __restrict__ Wv,
    const float* __restrict__ k_b, const float* __restrict__ v_b,
    unsigned short* __restrict__ kbT, unsigned short* __restrict__ vb) {
  __shared__ __align__(16) unsigned short xls[32][136];
  int b = blockIdx.y;
  int p0 = blockIdx.x * 32;
  int t = threadIdx.x;

  // ---- phase 1: sample ----
  {
    int pl = t & 31;          // position lane
    int cg = t >> 5;          // 0..7 -> 16 channels each
    int g = cg >> 2;          // group 0/1
    int pp = p0 + pl;
    int pidx = (b * 2 + g) * HW + pp;
    float gx = pos[2 * pidx], gy = pos[2 * pidx + 1];
    float x0f = floorf(gx), y0f = floorf(gy);
    float wx1 = gx - x0f, wx0 = 1.f - wx1;
    float wy1 = gy - y0f, wy0 = 1.f - wy1;
    int x0 = (int)x0f, y0 = (int)y0f;
    int x1 = x0 + 1, y1 = y0 + 1;
    float vx0 = (x0 >= 0 && x0 < 56) ? 1.f : 0.f;
    float vx1 = (x1 >= 0 && x1 < 56) ? 1.f : 0.f;
    float vy0 = (y0 >= 0 && y0 < 56) ? 1.f : 0.f;
    float vy1 = (y1 >= 0 && y1 < 56) ? 1.f : 0.f;
    int xc0 = min(max(x0, 0), 55), xc1 = min(max(x1, 0), 55);
    int yc0 = min(max(y0, 0), 55), yc1 = min(max(y1, 0), 55);
    float w00 = wx0 * wy0 * vx0 * vy0, w10 = wx1 * wy0 * vx1 * vy0;
    float w01 = wx0 * wy1 * vx0 * vy1, w11 = wx1 * wy1 * vx1 * vy1;
    int i00 = yc0 * 56 + xc0, i10 = yc0 * 56 + xc1;
    int i01 = yc1 * 56 + xc0, i11 = yc1 * 56 + xc1;
    const float* xb = x + ((size_t)b * 128 + g * 64 + (cg & 3) * 16) * HW;
    unsigned short tmp[16];
    #pragma unroll 4
    for (int i = 0; i < 16; ++i) {
      const float* xc = xb + (size_t)i * HW;
      tmp[i] = f2bf(w00 * xc[i00] + w10 * xc[i10] + w01 * xc[i01] + w11 * xc[i11]);
    }
    *(us8*)&xls[pl][cg * 16] = *(us8*)&tmp[0];
    *(us8*)&xls[pl][cg * 16 + 8] = *(us8*)&tmp[8];
  }
  __syncthreads();

  // ---- phase 2: K + V GEMM from LDS ----
  int w = t >> 6, l = t & 63;
  int lq = l & 15, h = l >> 4;

  s16x8 bfr[2][4];
  #pragma unroll
  for (int pf = 0; pf < 2; ++pf)
    #pragma unroll
    for (int k = 0; k < 4; ++k)
      bfr[pf][k] = *(const s16x8*)&xls[pf * 16 + lq][k * 32 + h * 8];

  // K projection: o-tiles og = w*2, w*2+1
  {
    f32x4 acc[2][2] = {};  // [ot][pf]
    #pragma unroll
    for (int k = 0; k < 4; ++k) {
      #pragma unroll
      for (int ot = 0; ot < 2; ++ot) {
        int og = w * 2 + ot;
        s16x8 af = *(const s16x8*)&Wk[(size_t)(og * 16 + lq) * 128 + k * 32 + h * 8];
        #pragma unroll
        for (int pf = 0; pf < 2; ++pf)
          acc[ot][pf] = __builtin_amdgcn_mfma_f32_16x16x32_bf16(
              af, bfr[pf][k], acc[ot][pf], 0, 0, 0);
      }
    }
    #pragma unroll
    for (int ot = 0; ot < 2; ++ot) {
      int og = w * 2 + ot;
      float4 bv = *(const float4*)&k_b[og * 16 + h * 4];
      #pragma unroll
      for (int pf = 0; pf < 2; ++pf) {
        int p = p0 + pf * 16 + lq;
        us4 rb;
        #pragma unroll
        for (int i = 0; i < 4; ++i) rb[i] = f2bf(acc[ot][pf][i] + bv[i]);
        *(us4*)&kbT[((size_t)b * HW + p) * 128 + og * 16 + h * 4] = rb;
      }
    }
  }
  // V projection
  {
    f32x4 acc[2][2] = {};
    #pragma unroll
    for (int k = 0; k < 4; ++k) {
      #pragma unroll
      for (int ot = 0; ot < 2; ++ot) {
        int og = w * 2 + ot;
        s16x8 af = *(const s16x8*)&Wv[(size_t)(og * 16 + lq) * 128 + k * 32 + h * 8];
        #pragma unroll
        for (int pf = 0; pf < 2; ++pf)
          acc[ot][pf] = __builtin_amdgcn_mfma_f32_16x16x32_bf16(
              af, bfr[pf][k], acc[ot][pf], 0, 0, 0);
      }
    }
    size_t cb = (size_t)b * 128 * HW;
    #pragma unroll
    for (int ot = 0; ot < 2; ++ot) {
      int og = w * 2 + ot;
      float4 bv = *(const float4*)&v_b[og * 16 + h * 4];
      #pragma unroll
      for (int pf = 0; pf < 2; ++pf) {
        int p = p0 + pf * 16 + lq;
        #pragma unroll
        for (int i = 0; i < 4; ++i)
          vb[cb + (size_t)(og * 16 + h * 4 + i) * HW + p] =
              f2bf(acc[ot][pf][i] + bv[i]);
      }
    }
  }
}

// ---------------------------------------------------------------------------
// o-projection MFMA hi/lo, o-split 2. grid (98, 8), block 128.
// ---------------------------------------------------------------------------
__global__ __launch_bounds__(128) void o_gemm_kernel(
    const unsigned short* __restrict__ AHi, const unsigned short* __restrict__ ALo,
    const unsigned short* __restrict__ WHi, const unsigned short* __restrict__ WLo,
    const float* __restrict__ bias, float* __restrict__ Outf) {
  int by = blockIdx.y;
  int b = by >> 1, oh = by & 1;
  int t = threadIdx.x;
  int w = t >> 6, l = t & 63;
  int lq = l & 15, h = l >> 4;
  int p = blockIdx.x * 32 + w * 16 + lq;

  s16x8 bH[4], bL[4];
  const unsigned short* bsH = AHi + ((size_t)b * HW + p) * 128 + h * 8;
  const unsigned short* bsL = ALo + ((size_t)b * HW + p) * 128 + h * 8;
  #pragma unroll
  for (int k = 0; k < 4; ++k) {
    bH[k] = *(const s16x8*)&bsH[k * 32];
    bL[k] = *(const s16x8*)&bsL[k * 32];
  }

  f32x4 acc[4] = {};
  #pragma unroll
  for (int k = 0; k < 4; ++k) {
    #pragma unroll
    for (int ot = 0; ot < 4; ++ot) {
      int og = oh * 4 + ot;
      size_t wi = (size_t)(og * 16 + lq) * 128 + k * 32 + h * 8;
      s16x8 aH = *(const s16x8*)&WHi[wi];
      s16x8 aL = *(const s16x8*)&WLo[wi];
      acc[ot] = __builtin_amdgcn_mfma_f32_16x16x32_bf16(aH, bH[k], acc[ot], 0, 0, 0);
      acc[ot] = __builtin_amdgcn_mfma_f32_16x16x32_bf16(aH, bL[k], acc[ot], 0, 0, 0);
      acc[ot] = __builtin_amdgcn_mfma_f32_16x16x32_bf16(aL, bH[k], acc[ot], 0, 0, 0);
    }
  }

  size_t cb = (size_t)b * 128 * HW;
  #pragma unroll
  for (int ot = 0; ot < 4; ++ot) {
    int og = oh * 4 + ot;
    float4 bv = *(const float4*)&bias[og * 16 + h * 4];
    #pragma unroll
    for (int i = 0; i < 4; ++i)
      Outf[cb + (size_t)(og * 16 + h * 4 + i) * HW + p] = acc[ot][i] + bv[i];
  }
}

// ---------------------------------------------------------------------------
// Offset branch v4 (r19): horizontal register reuse conv. grid (8, 56), 1024.
// ---------------------------------------------------------------------------
__global__ __launch_bounds__(1024) void offset_kernel(
    const float* __restrict__ q, const float* __restrict__ dw_w,
    const float* __restrict__ dw_b, const float* __restrict__ ln_g,
    const float* __restrict__ ln_b, const float* __restrict__ off_w,
    float* __restrict__ pos) {
  __shared__ float vs[64][65];
  __shared__ float mu_s[64], rs_s[64];
  __shared__ float part[16][64][2];
  int bg = blockIdx.x, h = blockIdx.y;
  int t = threadIdx.x;
  int b = bg >> 1, g = bg & 1;
  const float* qb = q + ((size_t)b * 128 + (size_t)g * 64) * HW;

  {
    int c = t >> 4;
    int wg = t & 15;
    if (wg < 14) {
      int w0 = wg * 4;
      float a0 = dw_b[c], a1 = a0, a2 = a0, a3 = a0;
      const float* qc = qb + (size_t)c * HW;
      const float* wc = dw_w + c * 49;
      #pragma unroll
      for (int ky = 0; ky < 7; ++ky) {
        int y = h + ky - 3;
        if (y >= 0 && y < 56) {
          float row[10];
          #pragma unroll
          for (int i = 0; i < 10; ++i) {
            int xx = w0 - 3 + i;
            row[i] = (xx >= 0 && xx < 56) ? qc[y * 56 + xx] : 0.f;
          }
          #pragma unroll
          for (int kx = 0; kx < 7; ++kx) {
            float wv = wc[ky * 7 + kx];
            a0 += row[kx] * wv;
            a1 += row[kx + 1] * wv;
            a2 += row[kx + 2] * wv;
            a3 += row[kx + 3] * wv;
          }
        }
      }
      vs[c][w0 + 0] = a0;
      vs[c][w0 + 1] = a1;
      vs[c][w0 + 2] = a2;
      vs[c][w0 + 3] = a3;
    } else {
      int base = 56 + (wg - 14) * 4;
      vs[c][base + 0] = 0.f;
      vs[c][base + 1] = 0.f;
      vs[c][base + 2] = 0.f;
      vs[c][base + 3] = 0.f;
    }
  }
  __syncthreads();

  int w = t & 63;
  int cq = t >> 6;
  if (cq == 0) {
    float sum = 0.f;
    #pragma unroll 8
    for (int c = 0; c < 64; ++c) sum += vs[c][w];
    float mu = sum * 0.015625f;
    float var = 0.f;
    #pragma unroll 8
    for (int c = 0; c < 64; ++c) { float d = vs[c][w] - mu; var += d * d; }
    mu_s[w] = mu;
    rs_s[w] = rsqrtf(var * 0.015625f + 1e-5f);
  }
  __syncthreads();

  {
    float mu = mu_s[w], rstd = rs_s[w];
    float oy = 0.f, ox = 0.f;
    #pragma unroll
    for (int i = 0; i < 4; ++i) {
      int c = cq * 4 + i;
      float hn = (vs[c][w] - mu) * rstd * ln_g[c] + ln_b[c];
      hn = 0.5f * hn * (1.f + erff(hn * 0.70710678118654752f));
      oy += off_w[c] * hn;
      ox += off_w[64 + c] * hn;
    }
    part[cq][w][0] = oy;
    part[cq][w][1] = ox;
  }
  __syncthreads();

  if (cq == 0 && w < 56) {
    float oy = 0.f, ox = 0.f;
    #pragma unroll
    for (int pw = 0; pw < 16; ++pw) {
      oy += part[pw][w][0];
      ox += part[pw][w][1];
    }
    float py = tanhf(oy) * (2.0f / 56.f) + ((h + 0.5f) * (2.f / 56.f) - 1.f);
    float px = tanhf(ox) * (2.0f / 56.f) + ((w + 0.5f) * (2.f / 56.f) - 1.f);
    int idx = bg * HW + h * 56 + w;
    pos[idx * 2 + 0] = (px + 1.f) * 0.5f * 55.f;
    pos[idx * 2 + 1] = (py + 1.f) * 0.5f * 55.f;
  }
}

// ---------------------------------------------------------------------------
// MFMA flash attention v15 (r15-exact, measured best). grid (49,16), block 128.
// ---------------------------------------------------------------------------
__global__ __launch_bounds__(128) void attn_mfma_kernel(
    const unsigned short* __restrict__ qT, const unsigned short* __restrict__ kT,
    const unsigned short* __restrict__ vbf, unsigned short* __restrict__ aoHi,
    unsigned short* __restrict__ aoLo) {
  __shared__ __align__(16) unsigned short Klds[2][64][40];
  __shared__ __align__(16) unsigned short Plds[2][2][16][68];  // [wave][frag]
  const int KSTEP = 64 * 40;
  int bh = blockIdx.y;
  int b = bh >> 2, hd = bh & 3;
  int t = threadIdx.x;
  int w = t >> 6, l = t & 63;
  int lq = l & 15, h = l >> 4;
  int q0 = blockIdx.x * 64 + w * 32;
  size_t vbase = (size_t)bh * 32 * HW;

  union S8 { s16x8 v; long long q[2]; unsigned short u[8]; };

  S8 qf0, qf1;
  qf0.v = *(const s16x8*)&qT[((size_t)b * HW + q0 + lq) * 128 + hd * 32 + h * 8];
  qf1.v = *(const s16x8*)&qT[((size_t)b * HW + q0 + 16 + lq) * 128 + hd * 32 + h * 8];

  int srow = t >> 1, sseg = (t & 1) * 16;
  const unsigned short* ksrc =
      kT + ((size_t)b * HW + srow) * 128 + hd * 32 + sseg;
  unsigned short* kdst = &Klds[0][srow][sseg];

  const unsigned short* vl = vbf + vbase + (size_t)lq * HW + h * 8;

  f32x4 oacc0[2] = {{0.f, 0.f, 0.f, 0.f}, {0.f, 0.f, 0.f, 0.f}};
  f32x4 oacc1[2] = {{0.f, 0.f, 0.f, 0.f}, {0.f, 0.f, 0.f, 0.f}};
  float lsum0 = 0.f, lsum1 = 0.f;

  S8 kr0, kr1, vreg[4];
  kr0.v = *(const s16x8*)&ksrc[0];
  kr1.v = *(const s16x8*)&ksrc[8];
  *(s16x8*)&kdst[0] = kr0.v;
  *(s16x8*)&kdst[8] = kr1.v;
  kr0.v = *(const s16x8*)&ksrc[(size_t)64 * 128];
  kr1.v = *(const s16x8*)&ksrc[(size_t)64 * 128 + 8];
  #pragma unroll
  for (int c = 0; c < 2; ++c)
    #pragma unroll
    for (int n = 0; n < 2; ++n)
      vreg[c * 2 + n].v = *(const s16x8*)&vl[(size_t)(n * 16) * HW + c * 32];
  asm volatile("s_waitcnt lgkmcnt(0)" ::: "memory");
  __builtin_amdgcn_s_barrier();

  for (int tix = 0; tix < 49; ++tix) {
    int cur = tix & 1;
    int kbV = (tix + 1 < 49) ? (tix + 1) * 64 : 0;
    int kbK = (tix + 2 < 49) ? (tix + 2) * 64 : 3072;

    f32x4 st0[4], st1[4];
    #pragma unroll
    for (int tt = 0; tt < 4; ++tt) {
      S8 af;
      af.v = *(const s16x8*)&Klds[cur][tt * 16 + lq][h * 8];
      st0[tt] = __builtin_amdgcn_mfma_f32_16x16x32_bf16(
          af.v, qf0.v, (f32x4){0.f, 0.f, 0.f, 0.f}, 0, 0, 0);
      st1[tt] = __builtin_amdgcn_mfma_f32_16x16x32_bf16(
          af.v, qf1.v, (f32x4){0.f, 0.f, 0.f, 0.f}, 0, 0, 0);
    }

    #pragma unroll
    for (int tt = 0; tt < 4; ++tt) {
      float a0, a1, a2, a3, b0, b1, b2, b3;
      asm("v_exp_f32 %0, %1" : "=v"(a0) : "v"(st0[tt][0]));
      asm("v_exp_f32 %0, %1" : "=v"(a1) : "v"(st0[tt][1]));
      asm("v_exp_f32 %0, %1" : "=v"(a2) : "v"(st0[tt][2]));
      asm("v_exp_f32 %0, %1" : "=v"(a3) : "v"(st0[tt][3]));
      asm("v_exp_f32 %0, %1" : "=v"(b0) : "v"(st1[tt][0]));
      asm("v_exp_f32 %0, %1" : "=v"(b1) : "v"(st1[tt][1]));
      asm("v_exp_f32 %0, %1" : "=v"(b2) : "v"(st1[tt][2]));
      asm("v_exp_f32 %0, %1" : "=v"(b3) : "v"(st1[tt][3]));
      lsum0 += (a0 + a1) + (a2 + a3);
      lsum1 += (b0 + b1) + (b2 + b3);
      unsigned int lo0, hi0, lo1, hi1;
      asm("v_cvt_pk_bf16_f32 %0, %1, %2" : "=v"(lo0) : "v"(a0), "v"(a1));
      asm("v_cvt_pk_bf16_f32 %0, %1, %2" : "=v"(hi0) : "v"(a2), "v"(a3));
      asm("v_cvt_pk_bf16_f32 %0, %1, %2" : "=v"(lo1) : "v"(b0), "v"(b1));
      asm("v_cvt_pk_bf16_f32 %0, %1, %2" : "=v"(hi1) : "v"(b2), "v"(b3));
      unsigned long long pk0 = (unsigned long long)lo0 | ((unsigned long long)hi0 << 32);
      unsigned long long pk1 = (unsigned long long)lo1 | ((unsigned long long)hi1 << 32);
      *(unsigned long long*)&Plds[w][0][lq][tt * 16 + h * 4] = pk0;
      *(unsigned long long*)&Plds[w][1][lq][tt * 16 + h * 4] = pk1;
    }

    #pragma unroll
    for (int c = 0; c < 2; ++c) {
      S8 pf0, pf1;
      pf0.q[0] = *(const long long*)&Plds[w][0][lq][c * 32 + h * 8];
      pf0.q[1] = *(const long long*)&Plds[w][0][lq][c * 32 + h * 8 + 4];
      pf1.q[0] = *(const long long*)&Plds[w][1][lq][c * 32 + h * 8];
      pf1.q[1] = *(const long long*)&Plds[w][1][lq][c * 32 + h * 8 + 4];
      #pragma unroll
      for (int n = 0; n < 2; ++n) {
        oacc0[n] = __builtin_amdgcn_mfma_f32_16x16x32_bf16(
            vreg[c * 2 + n].v, pf0.v, oacc0[n], 0, 0, 0);
        oacc1[n] = __builtin_amdgcn_mfma_f32_16x16x32_bf16(
            vreg[c * 2 + n].v, pf1.v, oacc1[n], 0, 0, 0);
      }
    }

    #pragma unroll
    for (int c = 0; c < 2; ++c)
      #pragma unroll
      for (int n = 0; n < 2; ++n)
        vreg[c * 2 + n].v =
            *(const s16x8*)&vl[(size_t)(n * 16) * HW + kbV + c * 32];

    *(s16x8*)(kdst + (cur ^ 1) * KSTEP) = kr0.v;
    *(s16x8*)(kdst + (cur ^ 1) * KSTEP + 8) = kr1.v;
    kr0.v = *(const s16x8*)&ksrc[(size_t)kbK * 128];
    kr1.v = *(const s16x8*)&ksrc[(size_t)kbK * 128 + 8];

    asm volatile("s_waitcnt lgkmcnt(0)" ::: "memory");
    __builtin_amdgcn_s_barrier();
  }

  lsum0 += __shfl_xor(lsum0, 16);
  lsum0 += __shfl_xor(lsum0, 32);
  lsum1 += __shfl_xor(lsum1, 16);
  lsum1 += __shfl_xor(lsum1, 32);
  float inv0 = 1.f / lsum0;
  float inv1 = 1.f / lsum1;
  #pragma unroll
  for (int f = 0; f < 2; ++f) {
    float inv = f ? inv1 : inv0;
    f32x4* oacc = f ? oacc1 : oacc0;
    size_t obase = ((size_t)b * HW + q0 + f * 16 + lq) * 128 + hd * 32;
    #pragma unroll
    for (int n = 0; n < 2; ++n) {
      us4 rh, rl;
      #pragma unroll
      for (int r = 0; r < 4; ++r) {
        float v = oacc[n][r] * inv;
        unsigned short hi = f2bf(v);
        rh[r] = hi;
        rl[r] = f2bf(v - bf2f(hi));
      }
      *(us4*)&aoHi[obase + n * 16 + h * 4] = rh;
      *(us4*)&aoLo[obase + n * 16 + h * 4] = rl;
    }
  }
}

// ---------------------------------------------------------------------------
extern "C" void kernel_launch(void* const* d_in, const int* in_sizes, int n_in,
                              void* d_out, int out_size, void* d_ws, size_t ws_size,
                              hipStream_t stream) {
  const float* x    = (const float*)d_in[0];
  const float* dw_w = (const float*)d_in[1];
  const float* dw_b = (const float*)d_in[2];
  const float* ln_g = (const float*)d_in[3];
  const float* ln_b = (const float*)d_in[4];
  const float* offw = (const float*)d_in[5];
  const float* q_w  = (const float*)d_in[6];
  const float* q_b  = (const float*)d_in[7];
  const float* k_w  = (const float*)d_in[8];
  const float* k_b  = (const float*)d_in[9];
  const float* v_w  = (const float*)d_in[10];
  const float* v_b  = (const float*)d_in[11];
  const float* o_w  = (const float*)d_in[12];
  const float* o_b  = (const float*)d_in[13];

  const size_t NE = 1605632;  // 4*128*3136
  float* ws  = (float*)d_ws;
  float* q   = ws;                   // fp32 q [c][p] (offset branch)
  float* pos = q + NE;               // 50176 floats
  unsigned short* qbT  = (unsigned short*)(pos + 50176);  // q bf16 [p][128] scaled
  unsigned short* kbT  = qbT + NE;   // k bf16 [p][128]
  unsigned short* vb   = kbT + NE;   // v bf16 [c][p]
  unsigned short* aoHi = vb + NE;    // attn out hi bf16 [p][128]
  unsigned short* aoLo = aoHi + NE;  // attn out lo bf16 [p][128]
  unsigned short* Wq   = aoLo + NE;  // 16384 each
  unsigned short* Wk   = Wq + 16384;
  unsigned short* Wv   = Wk + 16384;
  unsigned short* WoH  = Wv + 16384;
  unsigned short* WoL  = WoH + 16384;
  float* out = (float*)d_out;

  wconv_kernel<<<dim3(64, 4), 256, 0, stream>>>(q_w, k_w, v_w, o_w,
                                                Wq, Wk, Wv, WoH, WoL);
  gemm_q_kernel<<<dim3(98, 8), 128, 0, stream>>>(x, Wq, q_b, q, qbT);
  offset_kernel<<<dim3(8, 56), 1024, 0, stream>>>(q, dw_w, dw_b, ln_g, ln_b, offw, pos);
  sample_kv_kernel<<<dim3(98, 4), 256, 0, stream>>>(x, pos, Wk, Wv, k_b, v_b, kbT, vb);
  attn_mfma_kernel<<<dim3(49, 16), 128, 0, stream>>>(qbT, kbT, vb, aoHi, aoLo);
  o_gemm_kernel<<<dim3(98, 8), 128, 0, stream>>>(aoHi, aoLo, WoH, WoL, o_b, out);
}

// Round 21
// 129.103 us; speedup vs baseline: 1.1832x; 1.0005x over previous
//
#include <hip/hip_runtime.h>
#include <hip/hip_bf16.h>

#define HW 3136

typedef short s16x8 __attribute__((ext_vector_type(8)));
typedef float f32x4 __attribute__((ext_vector_type(4)));
typedef unsigned short us4 __attribute__((ext_vector_type(4)));
typedef unsigned short us8 __attribute__((ext_vector_type(8)));

__device__ inline unsigned short f2bf(float f) {
  union { float f; unsigned int u; } v; v.f = f;
  unsigned int r = v.u + 0x7fff + ((v.u >> 16) & 1);
  return (unsigned short)(r >> 16);
}
__device__ inline float bf2f(unsigned short b) {
  union { unsigned int u; float f; } v; v.u = (unsigned int)b << 16;
  return v.f;
}

// ---------------------------------------------------------------------------
// Weight prep. y=0..2: q_w/k_w/v_w -> plain bf16. y=3: o_w -> hi/lo bf16 pair.
// ---------------------------------------------------------------------------
__global__ __launch_bounds__(256) void wconv_kernel(
    const float* __restrict__ w0, const float* __restrict__ w1,
    const float* __restrict__ w2, const float* __restrict__ w3,
    unsigned short* __restrict__ o0, unsigned short* __restrict__ o1,
    unsigned short* __restrict__ o2, unsigned short* __restrict__ o3h,
    unsigned short* __restrict__ o3l) {
  int i = blockIdx.x * 256 + threadIdx.x;
  int y = blockIdx.y;
  if (y < 3) {
    const float* s = (y == 0) ? w0 : (y == 1) ? w1 : w2;
    unsigned short* d = (y == 0) ? o0 : (y == 1) ? o1 : o2;
    d[i] = f2bf(s[i]);
  } else {
    float x = w3[i];
    unsigned short hi = f2bf(x);
    o3h[i] = hi;
    o3l[i] = f2bf(x - bf2f(hi));
  }
}

// ---------------------------------------------------------------------------
// q-projection MFMA, fused transpose, o-split 2. grid (98, 8), block 128.
// ---------------------------------------------------------------------------
__global__ __launch_bounds__(128) void gemm_q_kernel(
    const float* __restrict__ x, const unsigned short* __restrict__ Wq,
    const float* __restrict__ bias, float* __restrict__ Outf,
    unsigned short* __restrict__ Outb) {
  int by = blockIdx.y;
  int b = by >> 1, oh = by & 1;
  int t = threadIdx.x;
  int w = t >> 6, l = t & 63;
  int lq = l & 15, h = l >> 4;
  int p = blockIdx.x * 32 + w * 16 + lq;

  union S8 { s16x8 v; unsigned short u[8]; };
  S8 bfr[4];
  const float* xs = x + (size_t)b * 128 * HW + p;
  #pragma unroll
  for (int k = 0; k < 4; ++k)
    #pragma unroll
    for (int j = 0; j < 8; ++j)
      bfr[k].u[j] = f2bf(xs[(size_t)(k * 32 + h * 8 + j) * HW]);

  f32x4 acc[4] = {};
  #pragma unroll
  for (int k = 0; k < 4; ++k) {
    #pragma unroll
    for (int ot = 0; ot < 4; ++ot) {
      int og = oh * 4 + ot;
      s16x8 af = *(const s16x8*)&Wq[(size_t)(og * 16 + lq) * 128 + k * 32 + h * 8];
      acc[ot] = __builtin_amdgcn_mfma_f32_16x16x32_bf16(af, bfr[k].v, acc[ot], 0, 0, 0);
    }
  }

  size_t cb = (size_t)b * 128 * HW;
  #pragma unroll
  for (int ot = 0; ot < 4; ++ot) {
    int og = oh * 4 + ot;
    float4 bv = *(const float4*)&bias[og * 16 + h * 4];
    float r[4] = {acc[ot][0] + bv.x, acc[ot][1] + bv.y,
                  acc[ot][2] + bv.z, acc[ot][3] + bv.w};
    #pragma unroll
    for (int i = 0; i < 4; ++i)
      Outf[cb + (size_t)(og * 16 + h * 4 + i) * HW + p] = r[i];
    const float S = 0.25503968151135f;  // rsqrt(32)*log2e
    us4 rb;
    #pragma unroll
    for (int i = 0; i < 4; ++i) rb[i] = f2bf(r[i] * S);
    *(us4*)&Outb[((size_t)b * HW + p) * 128 + og * 16 + h * 4] = rb;
  }
}

// ---------------------------------------------------------------------------
// FUSED bilinear-sample + K/V projection (r20). grid (98, 4), block 256.
// ---------------------------------------------------------------------------
__global__ __launch_bounds__(256) void sample_kv_kernel(
    const float* __restrict__ x, const float* __restrict__ pos,
    const unsigned short* __restrict__ Wk, const unsigned short* __restrict__ Wv,
    const float* __restrict__ k_b, const float* __restrict__ v_b,
    unsigned short* __restrict__ kbT, unsigned short* __restrict__ vb) {
  __shared__ __align__(16) unsigned short xls[32][136];
  int b = blockIdx.y;
  int p0 = blockIdx.x * 32;
  int t = threadIdx.x;

  {
    int pl = t & 31;
    int cg = t >> 5;
    int g = cg >> 2;
    int pp = p0 + pl;
    int pidx = (b * 2 + g) * HW + pp;
    float gx = pos[2 * pidx], gy = pos[2 * pidx + 1];
    float x0f = floorf(gx), y0f = floorf(gy);
    float wx1 = gx - x0f, wx0 = 1.f - wx1;
    float wy1 = gy - y0f, wy0 = 1.f - wy1;
    int x0 = (int)x0f, y0 = (int)y0f;
    int x1 = x0 + 1, y1 = y0 + 1;
    float vx0 = (x0 >= 0 && x0 < 56) ? 1.f : 0.f;
    float vx1 = (x1 >= 0 && x1 < 56) ? 1.f : 0.f;
    float vy0 = (y0 >= 0 && y0 < 56) ? 1.f : 0.f;
    float vy1 = (y1 >= 0 && y1 < 56) ? 1.f : 0.f;
    int xc0 = min(max(x0, 0), 55), xc1 = min(max(x1, 0), 55);
    int yc0 = min(max(y0, 0), 55), yc1 = min(max(y1, 0), 55);
    float w00 = wx0 * wy0 * vx0 * vy0, w10 = wx1 * wy0 * vx1 * vy0;
    float w01 = wx0 * wy1 * vx0 * vy1, w11 = wx1 * wy1 * vx1 * vy1;
    int i00 = yc0 * 56 + xc0, i10 = yc0 * 56 + xc1;
    int i01 = yc1 * 56 + xc0, i11 = yc1 * 56 + xc1;
    const float* xb = x + ((size_t)b * 128 + g * 64 + (cg & 3) * 16) * HW;
    unsigned short tmp[16];
    #pragma unroll 4
    for (int i = 0; i < 16; ++i) {
      const float* xc = xb + (size_t)i * HW;
      tmp[i] = f2bf(w00 * xc[i00] + w10 * xc[i10] + w01 * xc[i01] + w11 * xc[i11]);
    }
    *(us8*)&xls[pl][cg * 16] = *(us8*)&tmp[0];
    *(us8*)&xls[pl][cg * 16 + 8] = *(us8*)&tmp[8];
  }
  __syncthreads();

  int w = t >> 6, l = t & 63;
  int lq = l & 15, h = l >> 4;

  s16x8 bfr[2][4];
  #pragma unroll
  for (int pf = 0; pf < 2; ++pf)
    #pragma unroll
    for (int k = 0; k < 4; ++k)
      bfr[pf][k] = *(const s16x8*)&xls[pf * 16 + lq][k * 32 + h * 8];

  {
    f32x4 acc[2][2] = {};
    #pragma unroll
    for (int k = 0; k < 4; ++k) {
      #pragma unroll
      for (int ot = 0; ot < 2; ++ot) {
        int og = w * 2 + ot;
        s16x8 af = *(const s16x8*)&Wk[(size_t)(og * 16 + lq) * 128 + k * 32 + h * 8];
        #pragma unroll
        for (int pf = 0; pf < 2; ++pf)
          acc[ot][pf] = __builtin_amdgcn_mfma_f32_16x16x32_bf16(
              af, bfr[pf][k], acc[ot][pf], 0, 0, 0);
      }
    }
    #pragma unroll
    for (int ot = 0; ot < 2; ++ot) {
      int og = w * 2 + ot;
      float4 bv = *(const float4*)&k_b[og * 16 + h * 4];
      #pragma unroll
      for (int pf = 0; pf < 2; ++pf) {
        int p = p0 + pf * 16 + lq;
        us4 rb;
        #pragma unroll
        for (int i = 0; i < 4; ++i) rb[i] = f2bf(acc[ot][pf][i] + bv[i]);
        *(us4*)&kbT[((size_t)b * HW + p) * 128 + og * 16 + h * 4] = rb;
      }
    }
  }
  {
    f32x4 acc[2][2] = {};
    #pragma unroll
    for (int k = 0; k < 4; ++k) {
      #pragma unroll
      for (int ot = 0; ot < 2; ++ot) {
        int og = w * 2 + ot;
        s16x8 af = *(const s16x8*)&Wv[(size_t)(og * 16 + lq) * 128 + k * 32 + h * 8];
        #pragma unroll
        for (int pf = 0; pf < 2; ++pf)
          acc[ot][pf] = __builtin_amdgcn_mfma_f32_16x16x32_bf16(
              af, bfr[pf][k], acc[ot][pf], 0, 0, 0);
      }
    }
    size_t cb = (size_t)b * 128 * HW;
    #pragma unroll
    for (int ot = 0; ot < 2; ++ot) {
      int og = w * 2 + ot;
      float4 bv = *(const float4*)&v_b[og * 16 + h * 4];
      #pragma unroll
      for (int pf = 0; pf < 2; ++pf) {
        int p = p0 + pf * 16 + lq;
        #pragma unroll
        for (int i = 0; i < 4; ++i)
          vb[cb + (size_t)(og * 16 + h * 4 + i) * HW + p] =
              f2bf(acc[ot][pf][i] + bv[i]);
      }
    }
  }
}

// ---------------------------------------------------------------------------
// o-projection MFMA hi/lo, o-split 2. grid (98, 8), block 128.
// ---------------------------------------------------------------------------
__global__ __launch_bounds__(128) void o_gemm_kernel(
    const unsigned short* __restrict__ AHi, const unsigned short* __restrict__ ALo,
    const unsigned short* __restrict__ WHi, const unsigned short* __restrict__ WLo,
    const float* __restrict__ bias, float* __restrict__ Outf) {
  int by = blockIdx.y;
  int b = by >> 1, oh = by & 1;
  int t = threadIdx.x;
  int w = t >> 6, l = t & 63;
  int lq = l & 15, h = l >> 4;
  int p = blockIdx.x * 32 + w * 16 + lq;

  s16x8 bH[4], bL[4];
  const unsigned short* bsH = AHi + ((size_t)b * HW + p) * 128 + h * 8;
  const unsigned short* bsL = ALo + ((size_t)b * HW + p) * 128 + h * 8;
  #pragma unroll
  for (int k = 0; k < 4; ++k) {
    bH[k] = *(const s16x8*)&bsH[k * 32];
    bL[k] = *(const s16x8*)&bsL[k * 32];
  }

  f32x4 acc[4] = {};
  #pragma unroll
  for (int k = 0; k < 4; ++k) {
    #pragma unroll
    for (int ot = 0; ot < 4; ++ot) {
      int og = oh * 4 + ot;
      size_t wi = (size_t)(og * 16 + lq) * 128 + k * 32 + h * 8;
      s16x8 aH = *(const s16x8*)&WHi[wi];
      s16x8 aL = *(const s16x8*)&WLo[wi];
      acc[ot] = __builtin_amdgcn_mfma_f32_16x16x32_bf16(aH, bH[k], acc[ot], 0, 0, 0);
      acc[ot] = __builtin_amdgcn_mfma_f32_16x16x32_bf16(aH, bL[k], acc[ot], 0, 0, 0);
      acc[ot] = __builtin_amdgcn_mfma_f32_16x16x32_bf16(aL, bH[k], acc[ot], 0, 0, 0);
    }
  }

  size_t cb = (size_t)b * 128 * HW;
  #pragma unroll
  for (int ot = 0; ot < 4; ++ot) {
    int og = oh * 4 + ot;
    float4 bv = *(const float4*)&bias[og * 16 + h * 4];
    #pragma unroll
    for (int i = 0; i < 4; ++i)
      Outf[cb + (size_t)(og * 16 + h * 4 + i) * HW + p] = acc[ot][i] + bv[i];
  }
}

// ---------------------------------------------------------------------------
// Offset branch v4 (r19): horizontal register reuse conv. grid (8, 56), 1024.
// ---------------------------------------------------------------------------
__global__ __launch_bounds__(1024) void offset_kernel(
    const float* __restrict__ q, const float* __restrict__ dw_w,
    const float* __restrict__ dw_b, const float* __restrict__ ln_g,
    const float* __restrict__ ln_b, const float* __restrict__ off_w,
    float* __restrict__ pos) {
  __shared__ float vs[64][65];
  __shared__ float mu_s[64], rs_s[64];
  __shared__ float part[16][64][2];
  int bg = blockIdx.x, h = blockIdx.y;
  int t = threadIdx.x;
  int b = bg >> 1, g = bg & 1;
  const float* qb = q + ((size_t)b * 128 + (size_t)g * 64) * HW;

  {
    int c = t >> 4;
    int wg = t & 15;
    if (wg < 14) {
      int w0 = wg * 4;
      float a0 = dw_b[c], a1 = a0, a2 = a0, a3 = a0;
      const float* qc = qb + (size_t)c * HW;
      const float* wc = dw_w + c * 49;
      #pragma unroll
      for (int ky = 0; ky < 7; ++ky) {
        int y = h + ky - 3;
        if (y >= 0 && y < 56) {
          float row[10];
          #pragma unroll
          for (int i = 0; i < 10; ++i) {
            int xx = w0 - 3 + i;
            row[i] = (xx >= 0 && xx < 56) ? qc[y * 56 + xx] : 0.f;
          }
          #pragma unroll
          for (int kx = 0; kx < 7; ++kx) {
            float wv = wc[ky * 7 + kx];
            a0 += row[kx] * wv;
            a1 += row[kx + 1] * wv;
            a2 += row[kx + 2] * wv;
            a3 += row[kx + 3] * wv;
          }
        }
      }
      vs[c][w0 + 0] = a0;
      vs[c][w0 + 1] = a1;
      vs[c][w0 + 2] = a2;
      vs[c][w0 + 3] = a3;
    } else {
      int base = 56 + (wg - 14) * 4;
      vs[c][base + 0] = 0.f;
      vs[c][base + 1] = 0.f;
      vs[c][base + 2] = 0.f;
      vs[c][base + 3] = 0.f;
    }
  }
  __syncthreads();

  int w = t & 63;
  int cq = t >> 6;
  if (cq == 0) {
    float sum = 0.f;
    #pragma unroll 8
    for (int c = 0; c < 64; ++c) sum += vs[c][w];
    float mu = sum * 0.015625f;
    float var = 0.f;
    #pragma unroll 8
    for (int c = 0; c < 64; ++c) { float d = vs[c][w] - mu; var += d * d; }
    mu_s[w] = mu;
    rs_s[w] = rsqrtf(var * 0.015625f + 1e-5f);
  }
  __syncthreads();

  {
    float mu = mu_s[w], rstd = rs_s[w];
    float oy = 0.f, ox = 0.f;
    #pragma unroll
    for (int i = 0; i < 4; ++i) {
      int c = cq * 4 + i;
      float hn = (vs[c][w] - mu) * rstd * ln_g[c] + ln_b[c];
      hn = 0.5f * hn * (1.f + erff(hn * 0.70710678118654752f));
      oy += off_w[c] * hn;
      ox += off_w[64 + c] * hn;
    }
    part[cq][w][0] = oy;
    part[cq][w][1] = ox;
  }
  __syncthreads();

  if (cq == 0 && w < 56) {
    float oy = 0.f, ox = 0.f;
    #pragma unroll
    for (int pw = 0; pw < 16; ++pw) {
      oy += part[pw][w][0];
      ox += part[pw][w][1];
    }
    float py = tanhf(oy) * (2.0f / 56.f) + ((h + 0.5f) * (2.f / 56.f) - 1.f);
    float px = tanhf(ox) * (2.0f / 56.f) + ((w + 0.5f) * (2.f / 56.f) - 1.f);
    int idx = bg * HW + h * 56 + w;
    pos[idx * 2 + 0] = (px + 1.f) * 0.5f * 55.f;
    pos[idx * 2 + 1] = (py + 1.f) * 0.5f * 55.f;
  }
}

// ---------------------------------------------------------------------------
// MFMA flash attention v19: r15 structure + XCD-aware block swizzle (T1).
// grid 784 (flat, = 8 XCDs x 98); logical = (flat&7)*98 + (flat>>3), so each
// XCD serves only 2 of the 16 (b,head) pairs -> K/V working set 800 KB per
// XCD L2 (was 6.4 MB across all 16 -> thrash). block 128 = 2 waves.
// ---------------------------------------------------------------------------
__global__ __launch_bounds__(128) void attn_mfma_kernel(
    const unsigned short* __restrict__ qT, const unsigned short* __restrict__ kT,
    const unsigned short* __restrict__ vbf, unsigned short* __restrict__ aoHi,
    unsigned short* __restrict__ aoLo) {
  __shared__ __align__(16) unsigned short Klds[2][64][40];
  __shared__ __align__(16) unsigned short Plds[2][2][16][68];  // [wave][frag]
  const int KSTEP = 64 * 40;
  // XCD swizzle: 784 = 8*98, bijective remap
  int flat = blockIdx.x;
  int logical = (flat & 7) * 98 + (flat >> 3);
  int bh = logical / 49;          // 0..15
  int qtile = logical - bh * 49;  // 0..48
  int b = bh >> 2, hd = bh & 3;
  int t = threadIdx.x;
  int w = t >> 6, l = t & 63;
  int lq = l & 15, h = l >> 4;
  int q0 = qtile * 64 + w * 32;
  size_t vbase = (size_t)bh * 32 * HW;

  union S8 { s16x8 v; long long q[2]; unsigned short u[8]; };

  S8 qf0, qf1;
  qf0.v = *(const s16x8*)&qT[((size_t)b * HW + q0 + lq) * 128 + hd * 32 + h * 8];
  qf1.v = *(const s16x8*)&qT[((size_t)b * HW + q0 + 16 + lq) * 128 + hd * 32 + h * 8];

  int srow = t >> 1, sseg = (t & 1) * 16;
  const unsigned short* ksrc =
      kT + ((size_t)b * HW + srow) * 128 + hd * 32 + sseg;
  unsigned short* kdst = &Klds[0][srow][sseg];

  const unsigned short* vl = vbf + vbase + (size_t)lq * HW + h * 8;

  f32x4 oacc0[2] = {{0.f, 0.f, 0.f, 0.f}, {0.f, 0.f, 0.f, 0.f}};
  f32x4 oacc1[2] = {{0.f, 0.f, 0.f, 0.f}, {0.f, 0.f, 0.f, 0.f}};
  float lsum0 = 0.f, lsum1 = 0.f;

  S8 kr0, kr1, vreg[4];
  kr0.v = *(const s16x8*)&ksrc[0];
  kr1.v = *(const s16x8*)&ksrc[8];
  *(s16x8*)&kdst[0] = kr0.v;
  *(s16x8*)&kdst[8] = kr1.v;
  kr0.v = *(const s16x8*)&ksrc[(size_t)64 * 128];
  kr1.v = *(const s16x8*)&ksrc[(size_t)64 * 128 + 8];
  #pragma unroll
  for (int c = 0; c < 2; ++c)
    #pragma unroll
    for (int n = 0; n < 2; ++n)
      vreg[c * 2 + n].v = *(const s16x8*)&vl[(size_t)(n * 16) * HW + c * 32];
  asm volatile("s_waitcnt lgkmcnt(0)" ::: "memory");
  __builtin_amdgcn_s_barrier();

  for (int tix = 0; tix < 49; ++tix) {
    int cur = tix & 1;
    int kbV = (tix + 1 < 49) ? (tix + 1) * 64 : 0;
    int kbK = (tix + 2 < 49) ? (tix + 2) * 64 : 3072;

    f32x4 st0[4], st1[4];
    #pragma unroll
    for (int tt = 0; tt < 4; ++tt) {
      S8 af;
      af.v = *(const s16x8*)&Klds[cur][tt * 16 + lq][h * 8];
      st0[tt] = __builtin_amdgcn_mfma_f32_16x16x32_bf16(
          af.v, qf0.v, (f32x4){0.f, 0.f, 0.f, 0.f}, 0, 0, 0);
      st1[tt] = __builtin_amdgcn_mfma_f32_16x16x32_bf16(
          af.v, qf1.v, (f32x4){0.f, 0.f, 0.f, 0.f}, 0, 0, 0);
    }

    #pragma unroll
    for (int tt = 0; tt < 4; ++tt) {
      float a0, a1, a2, a3, b0, b1, b2, b3;
      asm("v_exp_f32 %0, %1" : "=v"(a0) : "v"(st0[tt][0]));
      asm("v_exp_f32 %0, %1" : "=v"(a1) : "v"(st0[tt][1]));
      asm("v_exp_f32 %0, %1" : "=v"(a2) : "v"(st0[tt][2]));
      asm("v_exp_f32 %0, %1" : "=v"(a3) : "v"(st0[tt][3]));
      asm("v_exp_f32 %0, %1" : "=v"(b0) : "v"(st1[tt][0]));
      asm("v_exp_f32 %0, %1" : "=v"(b1) : "v"(st1[tt][1]));
      asm("v_exp_f32 %0, %1" : "=v"(b2) : "v"(st1[tt][2]));
      asm("v_exp_f32 %0, %1" : "=v"(b3) : "v"(st1[tt][3]));
      lsum0 += (a0 + a1) + (a2 + a3);
      lsum1 += (b0 + b1) + (b2 + b3);
      unsigned int lo0, hi0, lo1, hi1;
      asm("v_cvt_pk_bf16_f32 %0, %1, %2" : "=v"(lo0) : "v"(a0), "v"(a1));
      asm("v_cvt_pk_bf16_f32 %0, %1, %2" : "=v"(hi0) : "v"(a2), "v"(a3));
      asm("v_cvt_pk_bf16_f32 %0, %1, %2" : "=v"(lo1) : "v"(b0), "v"(b1));
      asm("v_cvt_pk_bf16_f32 %0, %1, %2" : "=v"(hi1) : "v"(b2), "v"(b3));
      unsigned long long pk0 = (unsigned long long)lo0 | ((unsigned long long)hi0 << 32);
      unsigned long long pk1 = (unsigned long long)lo1 | ((unsigned long long)hi1 << 32);
      *(unsigned long long*)&Plds[w][0][lq][tt * 16 + h * 4] = pk0;
      *(unsigned long long*)&Plds[w][1][lq][tt * 16 + h * 4] = pk1;
    }

    #pragma unroll
    for (int c = 0; c < 2; ++c) {
      S8 pf0, pf1;
      pf0.q[0] = *(const long long*)&Plds[w][0][lq][c * 32 + h * 8];
      pf0.q[1] = *(const long long*)&Plds[w][0][lq][c * 32 + h * 8 + 4];
      pf1.q[0] = *(const long long*)&Plds[w][1][lq][c * 32 + h * 8];
      pf1.q[1] = *(const long long*)&Plds[w][1][lq][c * 32 + h * 8 + 4];
      #pragma unroll
      for (int n = 0; n < 2; ++n) {
        oacc0[n] = __builtin_amdgcn_mfma_f32_16x16x32_bf16(
            vreg[c * 2 + n].v, pf0.v, oacc0[n], 0, 0, 0);
        oacc1[n] = __builtin_amdgcn_mfma_f32_16x16x32_bf16(
            vreg[c * 2 + n].v, pf1.v, oacc1[n], 0, 0, 0);
      }
    }

    #pragma unroll
    for (int c = 0; c < 2; ++c)
      #pragma unroll
      for (int n = 0; n < 2; ++n)
        vreg[c * 2 + n].v =
            *(const s16x8*)&vl[(size_t)(n * 16) * HW + kbV + c * 32];

    *(s16x8*)(kdst + (cur ^ 1) * KSTEP) = kr0.v;
    *(s16x8*)(kdst + (cur ^ 1) * KSTEP + 8) = kr1.v;
    kr0.v = *(const s16x8*)&ksrc[(size_t)kbK * 128];
    kr1.v = *(const s16x8*)&ksrc[(size_t)kbK * 128 + 8];

    asm volatile("s_waitcnt lgkmcnt(0)" ::: "memory");
    __builtin_amdgcn_s_barrier();
  }

  lsum0 += __shfl_xor(lsum0, 16);
  lsum0 += __shfl_xor(lsum0, 32);
  lsum1 += __shfl_xor(lsum1, 16);
  lsum1 += __shfl_xor(lsum1, 32);
  float inv0 = 1.f / lsum0;
  float inv1 = 1.f / lsum1;
  #pragma unroll
  for (int f = 0; f < 2; ++f) {
    float inv = f ? inv1 : inv0;
    f32x4* oacc = f ? oacc1 : oacc0;
    size_t obase = ((size_t)b * HW + q0 + f * 16 + lq) * 128 + hd * 32;
    #pragma unroll
    for (int n = 0; n < 2; ++n) {
      us4 rh, rl;
      #pragma unroll
      for (int r = 0; r < 4; ++r) {
        float v = oacc[n][r] * inv;
        unsigned short hi = f2bf(v);
        rh[r] = hi;
        rl[r] = f2bf(v - bf2f(hi));
      }
      *(us4*)&aoHi[obase + n * 16 + h * 4] = rh;
      *(us4*)&aoLo[obase + n * 16 + h * 4] = rl;
    }
  }
}

// ---------------------------------------------------------------------------
extern "C" void kernel_launch(void* const* d_in, const int* in_sizes, int n_in,
                              void* d_out, int out_size, void* d_ws, size_t ws_size,
                              hipStream_t stream) {
  const float* x    = (const float*)d_in[0];
  const float* dw_w = (const float*)d_in[1];
  const float* dw_b = (const float*)d_in[2];
  const float* ln_g = (const float*)d_in[3];
  const float* ln_b = (const float*)d_in[4];
  const float* offw = (const float*)d_in[5];
  const float* q_w  = (const float*)d_in[6];
  const float* q_b  = (const float*)d_in[7];
  const float* k_w  = (const float*)d_in[8];
  const float* k_b  = (const float*)d_in[9];
  const float* v_w  = (const float*)d_in[10];
  const float* v_b  = (const float*)d_in[11];
  const float* o_w  = (const float*)d_in[12];
  const float* o_b  = (const float*)d_in[13];

  const size_t NE = 1605632;  // 4*128*3136
  float* ws  = (float*)d_ws;
  float* q   = ws;                   // fp32 q [c][p] (offset branch)
  float* pos = q + NE;               // 50176 floats
  unsigned short* qbT  = (unsigned short*)(pos + 50176);  // q bf16 [p][128] scaled
  unsigned short* kbT  = qbT + NE;   // k bf16 [p][128]
  unsigned short* vb   = kbT + NE;   // v bf16 [c][p]
  unsigned short* aoHi = vb + NE;    // attn out hi bf16 [p][128]
  unsigned short* aoLo = aoHi + NE;  // attn out lo bf16 [p][128]
  unsigned short* Wq   = aoLo + NE;  // 16384 each
  unsigned short* Wk   = Wq + 16384;
  unsigned short* Wv   = Wk + 16384;
  unsigned short* WoH  = Wv + 16384;
  unsigned short* WoL  = WoH + 16384;
  float* out = (float*)d_out;

  wconv_kernel<<<dim3(64, 4), 256, 0, stream>>>(q_w, k_w, v_w, o_w,
                                                Wq, Wk, Wv, WoH, WoL);
  gemm_q_kernel<<<dim3(98, 8), 128, 0, stream>>>(x, Wq, q_b, q, qbT);
  offset_kernel<<<dim3(8, 56), 1024, 0, stream>>>(q, dw_w, dw_b, ln_g, ln_b, offw, pos);
  sample_kv_kernel<<<dim3(98, 4), 256, 0, stream>>>(x, pos, Wk, Wv, k_b, v_b, kbT, vb);
  attn_mfma_kernel<<<dim3(784), 128, 0, stream>>>(qbT, kbT, vb, aoHi, aoLo);
  o_gemm_kernel<<<dim3(98, 8), 128, 0, stream>>>(aoHi, aoLo, WoH, WoL, o_b, out);
}